// Round 4
// baseline (251.969 us; speedup 1.0000x reference)
//
#include <hip/hip_runtime.h>
#include <stdint.h>

#define SLEN 2048
#define DMODEL 1024
#define NHEADS 16
#define MTOT 8192   // 4 * 2048

typedef short s16x8 __attribute__((ext_vector_type(8)));
typedef short s16x4 __attribute__((ext_vector_type(4)));
typedef float f32x4 __attribute__((ext_vector_type(4)));
typedef unsigned u32x2 __attribute__((ext_vector_type(2)));

static __device__ __forceinline__ unsigned short f2bf(float f) {
  unsigned u = __builtin_bit_cast(unsigned, f);
  u += 0x7fffu + ((u >> 16) & 1u);           // RNE
  return (unsigned short)(u >> 16);
}

static __device__ __forceinline__ unsigned cvt_pk_bf16(float lo, float hi) {
  unsigned r;
  asm("v_cvt_pk_bf16_f32 %0, %1, %2" : "=v"(r) : "v"(lo), "v"(hi));
  return r;
}

static __device__ __forceinline__ void gload_lds16(const void* g, void* l) {
  __builtin_amdgcn_global_load_lds((__attribute__((address_space(1))) void*)g,
                                   (__attribute__((address_space(3))) void*)l,
                                   16, 0, 0);
}

#define MFMA16(a, b, c) __builtin_amdgcn_mfma_f32_16x16x32_bf16(a, b, c, 0, 0, 0)

// ---------------- RoPE cos/sin table: [2048][32] each ----------------
__global__ void __launch_bounds__(256) rope_table(const int* __restrict__ pos,
                                                  float* __restrict__ ctab,
                                                  float* __restrict__ stab) {
  int g = blockIdx.x * 256 + threadIdx.x;     // 65536 total
  int s = g >> 5, i = g & 31;
  float p = (float)pos[s];
  float ang = p * exp2f(-(float)i * 0.41524101186092029f);
  ctab[g] = cosf(ang);
  stab[g] = sinf(ang);
}

// ---------------- fp32 -> bf16 convert (x8 vectorized) ----------------
__global__ void __launch_bounds__(256) cvt_f32_bf16(const float* __restrict__ src,
                                                    unsigned short* __restrict__ dst,
                                                    int n8) {
  int i = blockIdx.x * 256 + threadIdx.x;
  if (i >= n8) return;
  f32x4 a = ((const f32x4*)src)[i * 2];
  f32x4 b = ((const f32x4*)src)[i * 2 + 1];
  s16x8 o;
#pragma unroll
  for (int j = 0; j < 4; ++j) o[j] = (short)f2bf(a[j]);
#pragma unroll
  for (int j = 0; j < 4; ++j) o[4 + j] = (short)f2bf(b[j]);
  ((s16x8*)dst)[i] = o;
}

// all four weight matrices in one dispatch (grid.y selects)
__global__ void __launch_bounds__(256) cvt_weights(const float* __restrict__ w0,
                                                   const float* __restrict__ w1,
                                                   const float* __restrict__ w2,
                                                   const float* __restrict__ w3,
                                                   unsigned short* __restrict__ d0,
                                                   unsigned short* __restrict__ d1,
                                                   unsigned short* __restrict__ d2,
                                                   unsigned short* __restrict__ d3) {
  int which = blockIdx.y;
  const float* src = which == 0 ? w0 : which == 1 ? w1 : which == 2 ? w2 : w3;
  unsigned short* dst = which == 0 ? d0 : which == 1 ? d1 : which == 2 ? d2 : d3;
  int i = blockIdx.x * 256 + threadIdx.x;     // 131072 per matrix
  f32x4 a = ((const f32x4*)src)[i * 2];
  f32x4 b = ((const f32x4*)src)[i * 2 + 1];
  s16x8 o;
#pragma unroll
  for (int j = 0; j < 4; ++j) o[j] = (short)f2bf(a[j]);
#pragma unroll
  for (int j = 0; j < 4; ++j) o[4 + j] = (short)f2bf(b[j]);
  ((s16x8*)dst)[i] = o;
}

// ---------------- GEMM: C[M=8192][N=1024] = A[M][K] * B[N][K]^T --------------
// MODE 0: store f32 row-major (final Wo projection)
// MODE 1: RoPE epilogue, scale, store bf16 to [bh][s][64]   (Q and K)
// MODE 2: store bf16 transposed V^T [bh][d][s]              (V)
// Grid is always (8, 64) = 512 blocks. XCD y-clustering remap: XCD k gets
// by in [8k, 8k+8) so all 8 bx-blocks of a row-panel share one L2 ->
// A-panel fetched once per y.
template<int MODE>
__global__ void __launch_bounds__(256) gemm_nt(const unsigned short* __restrict__ A,
                                               const unsigned short* __restrict__ B,
                                               void* __restrict__ dstv,
                                               const float* __restrict__ ctab,
                                               const float* __restrict__ stab,
                                               float scale) {
  __shared__ unsigned short ldsA[2][128 * 32];
  __shared__ unsigned short ldsB[2][128 * 32];
  const int tid = threadIdx.x;
  const int lane = tid & 63;
  const int wave = tid >> 6;
  const int wm = wave >> 1, wn = wave & 1;

  int flat = blockIdx.y * 8 + blockIdx.x;
  int logical = (flat & 7) * 64 + (flat >> 3);
  const int m0 = (logical >> 3) * 128;
  const int n0 = (logical & 7) * 128;
  const int l15 = lane & 15, lhi = lane >> 4;

  f32x4 acc[4][4] = {};

  auto stage = [&](int buf, int kt) {
    const int kbase = kt * 32;
#pragma unroll
    for (int issue = 0; issue < 2; ++issue) {
      int c = issue * 256 + wave * 64 + lane;   // chunk id 0..511
      int row = c >> 2, kc = c & 3;
      int kcg = kc ^ ((row >> 1) & 3);          // source chunk for this slot
      gload_lds16(A + (size_t)(m0 + row) * 1024 + kbase + kcg * 8,
                  &ldsA[buf][(issue * 256 + wave * 64) * 8]);
      gload_lds16(B + (size_t)(n0 + row) * 1024 + kbase + kcg * 8,
                  &ldsB[buf][(issue * 256 + wave * 64) * 8]);
    }
  };

  stage(0, 0);
  for (int kt = 0; kt < 32; ++kt) {
    __syncthreads();
    if (kt + 1 < 32) stage((kt + 1) & 1, kt + 1);
    const int buf = kt & 1;
    s16x8 af[4], bf[4];
#pragma unroll
    for (int mi = 0; mi < 4; ++mi) {
      int row = wm * 64 + mi * 16 + l15;
      int kc = lhi ^ ((row >> 1) & 3);
      af[mi] = *(const s16x8*)&ldsA[buf][row * 32 + kc * 8];
    }
#pragma unroll
    for (int ni = 0; ni < 4; ++ni) {
      int row = wn * 64 + ni * 16 + l15;
      int kc = lhi ^ ((row >> 1) & 3);
      bf[ni] = *(const s16x8*)&ldsB[buf][row * 32 + kc * 8];
    }
#pragma unroll
    for (int mi = 0; mi < 4; ++mi)
#pragma unroll
      for (int ni = 0; ni < 4; ++ni)
        acc[mi][ni] = MFMA16(af[mi], bf[ni], acc[mi][ni]);
  }

  // C layout: col = lane&15, row = (lane>>4)*4 + i
  if constexpr (MODE == 0) {
    float* dst = (float*)dstv;
#pragma unroll
    for (int mi = 0; mi < 4; ++mi)
#pragma unroll
      for (int ni = 0; ni < 4; ++ni)
#pragma unroll
        for (int i = 0; i < 4; ++i) {
          int r = m0 + wm * 64 + mi * 16 + lhi * 4 + i;
          int n = n0 + wn * 64 + ni * 16 + l15;
          dst[(size_t)r * 1024 + n] = acc[mi][ni][i];
        }
  } else if constexpr (MODE == 1) {
    unsigned short* dst = (unsigned short*)dstv;
#pragma unroll
    for (int mi = 0; mi < 4; ++mi)
#pragma unroll
      for (int ni = 0; ni < 4; ++ni)
#pragma unroll
        for (int i = 0; i < 4; ++i) {
          int r = m0 + wm * 64 + mi * 16 + lhi * 4 + i;
          int n = n0 + wn * 64 + ni * 16 + l15;
          float v = acc[mi][ni][i];
          float p = __shfl_xor(v, 1);           // RoPE partner
          int s = r & (SLEN - 1);
          int d = n & 63;
          int fi = d >> 1;
          float c = ctab[s * 32 + fi], sn = stab[s * 32 + fi];
          float o = (d & 1) ? (p * sn + v * c) : (v * c - p * sn);
          o *= scale;
          int b = r >> 11, h = n >> 6;
          dst[((size_t)(b * NHEADS + h) * SLEN + s) * 64 + d] = f2bf(o);
        }
  } else {  // MODE 2: V^T [bh][d][s]
    unsigned short* dst = (unsigned short*)dstv;
#pragma unroll
    for (int mi = 0; mi < 4; ++mi)
#pragma unroll
      for (int ni = 0; ni < 4; ++ni) {
        int r0 = m0 + wm * 64 + mi * 16 + lhi * 4;
        int n = n0 + wn * 64 + ni * 16 + l15;
        int b = r0 >> 11, s0 = r0 & (SLEN - 1);
        int h = n >> 6, d = n & 63;
        s16x4 pk;
#pragma unroll
        for (int i = 0; i < 4; ++i) pk[i] = (short)f2bf(acc[mi][ni][i]);
        *(s16x4*)&dst[((size_t)(b * NHEADS + h) * 64 + d) * SLEN + s0] = pk;
      }
  }
}

// ---------------- causal flash attention, v4 ----------------
// Q,K: [bh][s][64] bf16 (Q pre-scaled by 0.125*log2e), Vt: [bh][64][s] bf16.
// 2048 blocks x 128 threads (2 waves). Block handles ONE 64-row q-tile;
// LPT dispatch order (t=31 first within each XCD chunk). Wave w owns 32
// q-cols. K staged via global_load_lds dbuf; V fully prefetched from global
// per k-tile; defer-rescale (skip accT rescale when tile max <= running max).
__global__ void __launch_bounds__(128, 3) flash_attn(const unsigned short* __restrict__ Q,
                                                     const unsigned short* __restrict__ K,
                                                     const unsigned short* __restrict__ Vt,
                                                     unsigned short* __restrict__ Obf) {
  __shared__ unsigned short Kbuf[2][64 * 64];   // 16 KB, 16B-granule swizzle ^(row&7)
  __shared__ unsigned short Pbuf[2][32 * 64];   // 8 KB, per-wave private

  const int tid = threadIdx.x, lane = tid & 63, w = tid >> 6;
  const int l15 = lane & 15, lhi = lane >> 4;
  const int swz = l15 & 7;

  // XCD chunking (XCD k gets bh in [8k,8k+8)) + LPT (t descending)
  int id = blockIdx.x;                          // 0..2047
  int logical = (id & 7) * 256 + (id >> 3);
  const int bh = logical >> 5;                  // 0..63
  const int t = 31 - (logical & 31);            // big tiles dispatched first
  const int b = bh >> 4, h = bh & 15;

  const unsigned short* Qb = Q + (size_t)bh * SLEN * 64;
  const unsigned short* Kb = K + (size_t)bh * SLEN * 64;
  const unsigned short* Vb = Vt + (size_t)bh * 64 * SLEN;

  const int qbase = t * 64;
  const int nt = t + 1;

  // stage one 64x64 K tile; source pre-swizzled so LDS reads are conflict-free
  auto stageK = [&](int buf, int k0) {
#pragma unroll
    for (int j = 0; j < 4; ++j) {
      int c = j * 128 + tid;                    // 16B chunk 0..511
      int row = c >> 3, cg = c & 7;
      gload_lds16(Kb + (size_t)(k0 + row) * 64 + ((cg ^ (row & 7)) * 8),
                  &Kbuf[buf][c * 8]);
    }
  };

  // Q B-fragments: wave w owns q-cols [w*32, w*32+32)
  s16x8 qf[2][2];
#pragma unroll
  for (int nq = 0; nq < 2; ++nq)
#pragma unroll
    for (int kd = 0; kd < 2; ++kd)
      qf[nq][kd] = *(const s16x8*)&Qb[(size_t)(qbase + w * 32 + nq * 16 + l15) * 64 + kd * 32 + lhi * 8];

  f32x4 accT[4][2] = {};                        // O^T: row d, col q (lane-local q = l15)
  float m_run[2] = {-3.0e38f, -3.0e38f};
  float l_run[2] = {0.f, 0.f};

  stageK(0, 0);
  for (int kt = 0; kt < nt; ++kt) {
    const int cur = kt & 1;
    const int k0 = kt * 64;
    __syncthreads();                            // vmcnt drain: stage(kt) landed; other buf free
    if (kt + 1 < nt) stageK(cur ^ 1, (kt + 1) * 64);

    // prefetch ALL V fragments for this tile (hidden under QK^T + softmax)
    s16x8 vf[2][4];
#pragma unroll
    for (int ks = 0; ks < 2; ++ks)
#pragma unroll
      for (int md = 0; md < 4; ++md)
        vf[ks][md] = *(const s16x8*)&Vb[(size_t)(md * 16 + l15) * SLEN + k0 + ks * 32 + lhi * 8];

    // K A-fragments from LDS (swizzled)
    s16x8 kf[4][2];
#pragma unroll
    for (int mk = 0; mk < 4; ++mk) {
      int r = mk * 16 + l15;
#pragma unroll
      for (int kd = 0; kd < 2; ++kd)
        kf[mk][kd] = *(const s16x8*)&Kbuf[cur][r * 64 + (((kd * 4 + lhi) ^ swz) * 8)];
    }

    // S^T = K * Q^T
    f32x4 sacc[4][2] = {};
#pragma unroll
    for (int mk = 0; mk < 4; ++mk)
#pragma unroll
      for (int nq = 0; nq < 2; ++nq) {
        sacc[mk][nq] = MFMA16(kf[mk][0], qf[nq][0], sacc[mk][nq]);
        sacc[mk][nq] = MFMA16(kf[mk][1], qf[nq][1], sacc[mk][nq]);
      }

    const bool diag = (kt == nt - 1);
    float fac[2];
#pragma unroll
    for (int nq = 0; nq < 2; ++nq) {
      const int qloc = w * 32 + nq * 16 + l15;
      if (diag) {
#pragma unroll
        for (int mk = 0; mk < 4; ++mk)
#pragma unroll
          for (int i = 0; i < 4; ++i)
            if (mk * 16 + lhi * 4 + i > qloc) sacc[mk][nq][i] = -3.0e38f;
      }
      float mx = sacc[0][nq][0];
#pragma unroll
      for (int mk = 0; mk < 4; ++mk)
#pragma unroll
        for (int i = 0; i < 4; ++i) mx = fmaxf(mx, sacc[mk][nq][i]);
      mx = fmaxf(mx, __shfl_xor(mx, 16));
      mx = fmaxf(mx, __shfl_xor(mx, 32));
      // defer-rescale: only rescale when the running max actually grows
      if (!__all(mx <= m_run[nq])) {
        const float mnew = fmaxf(m_run[nq], mx);
        const float facv = exp2f(m_run[nq] - mnew);
        m_run[nq] = mnew;
        l_run[nq] *= facv;
#pragma unroll
        for (int md = 0; md < 4; ++md)
#pragma unroll
          for (int i = 0; i < 4; ++i) accT[md][nq][i] *= facv;
      }
      float s0 = 0.f, s1 = 0.f;
#pragma unroll
      for (int mk = 0; mk < 4; ++mk) {
        f32x4 p;
#pragma unroll
        for (int i = 0; i < 4; ++i) p[i] = exp2f(sacc[mk][nq][i] - m_run[nq]);
        s0 += p[0] + p[1];
        s1 += p[2] + p[3];
        sacc[mk][nq] = p;
      }
      float sum = s0 + s1;
      sum += __shfl_xor(sum, 16);
      sum += __shfl_xor(sum, 32);
      l_run[nq] += sum;
    }

    // P -> bf16 -> private LDS [32 q][64 k], 16B-granule swizzle ^(q&7)
#pragma unroll
    for (int nq = 0; nq < 2; ++nq)
#pragma unroll
      for (int mk = 0; mk < 4; ++mk) {
        int q = nq * 16 + l15;
        int kog = mk * 2 + (lhi >> 1);
        int off = q * 64 + ((kog ^ swz) * 8) + (lhi & 1) * 4;
        u32x2 pk;
        pk[0] = cvt_pk_bf16(sacc[mk][nq][0], sacc[mk][nq][1]);
        pk[1] = cvt_pk_bf16(sacc[mk][nq][2], sacc[mk][nq][3]);
        *(u32x2*)&Pbuf[w][off] = pk;
      }

    // PV: O^T += Vt_frag (A) * P^T (B)
#pragma unroll
    for (int ks = 0; ks < 2; ++ks) {
      s16x8 pa[2];
#pragma unroll
      for (int nq = 0; nq < 2; ++nq) {
        int q = nq * 16 + l15;
        pa[nq] = *(const s16x8*)&Pbuf[w][q * 64 + (((ks * 4 + lhi) ^ swz) * 8)];
      }
#pragma unroll
      for (int md = 0; md < 4; ++md)
#pragma unroll
        for (int nq = 0; nq < 2; ++nq)
          accT[md][nq] = MFMA16(vf[ks][md], pa[nq], accT[md][nq]);
    }
  }

  // normalize (lane-local) and store O^T -> [b][s][h*64+d]
#pragma unroll
  for (int nq = 0; nq < 2; ++nq) {
    float linv = 1.f / l_run[nq];
    int qg = qbase + w * 32 + nq * 16 + l15;
#pragma unroll
    for (int md = 0; md < 4; ++md) {
      u32x2 pk;
      pk[0] = cvt_pk_bf16(accT[md][nq][0] * linv, accT[md][nq][1] * linv);
      pk[1] = cvt_pk_bf16(accT[md][nq][2] * linv, accT[md][nq][3] * linv);
      *(u32x2*)&Obf[((size_t)(b * SLEN + qg)) * DMODEL + h * 64 + md * 16 + lhi * 4] = pk;
    }
  }
}

extern "C" void kernel_launch(void* const* d_in, const int* in_sizes, int n_in,
                              void* d_out, int out_size, void* d_ws, size_t ws_size,
                              hipStream_t stream) {
  const float* x  = (const float*)d_in[0];
  const float* Wq = (const float*)d_in[1];
  const float* Wk = (const float*)d_in[2];
  const float* Wv = (const float*)d_in[3];
  const float* Wo = (const float*)d_in[4];
  const int* pos  = (const int*)d_in[5];
  float* out = (float*)d_out;

  char* ws = (char*)d_ws;
  size_t off = 0;
  auto take = [&](size_t bytes) {
    char* p = ws + off;
    off += (bytes + 255) & ~(size_t)255;
    return p;
  };
  unsigned short* xbf  = (unsigned short*)take((size_t)MTOT * DMODEL * 2);
  unsigned short* wqbf = (unsigned short*)take((size_t)DMODEL * DMODEL * 2);
  unsigned short* wkbf = (unsigned short*)take((size_t)DMODEL * DMODEL * 2);
  unsigned short* wvbf = (unsigned short*)take((size_t)DMODEL * DMODEL * 2);
  unsigned short* wobf = (unsigned short*)take((size_t)DMODEL * DMODEL * 2);
  unsigned short* Qs   = (unsigned short*)take((size_t)64 * SLEN * 64 * 2);
  unsigned short* Ks   = (unsigned short*)take((size_t)64 * SLEN * 64 * 2);
  unsigned short* Vt   = (unsigned short*)take((size_t)64 * 64 * SLEN * 2);
  unsigned short* Obf  = (unsigned short*)take((size_t)MTOT * DMODEL * 2);
  float* ctab = (float*)take((size_t)SLEN * 32 * 4);
  float* stab = (float*)take((size_t)SLEN * 32 * 4);

  rope_table<<<256, 256, 0, stream>>>(pos, ctab, stab);
  cvt_f32_bf16<<<4096, 256, 0, stream>>>(x, xbf, MTOT * DMODEL / 8);
  cvt_weights<<<dim3(512, 4), 256, 0, stream>>>(Wq, Wk, Wv, Wo, wqbf, wkbf, wvbf, wobf);

  dim3 gg(DMODEL / 128, MTOT / 128);  // (8, 64)
  // Q: RoPE + fold softmax scale 0.125 * log2(e)
  gemm_nt<1><<<gg, 256, 0, stream>>>(xbf, wqbf, Qs, ctab, stab, 0.18033688011112042f);
  // K: RoPE only
  gemm_nt<1><<<gg, 256, 0, stream>>>(xbf, wkbf, Ks, ctab, stab, 1.0f);
  // V: transposed store
  gemm_nt<2><<<gg, 256, 0, stream>>>(xbf, wvbf, Vt, ctab, stab, 1.0f);

  flash_attn<<<2048, 128, 0, stream>>>(Qs, Ks, Vt, Obf);

  // final projection, fp32 output
  gemm_nt<0><<<gg, 256, 0, stream>>>(Obf, wobf, out, nullptr, nullptr, 1.0f);
}

// Round 5
// 228.047 us; speedup vs baseline: 1.1049x; 1.1049x over previous
//
#include <hip/hip_runtime.h>
#include <stdint.h>

#define SLEN 2048
#define DMODEL 1024
#define NHEADS 16
#define MTOT 8192   // 4 * 2048

typedef short s16x8 __attribute__((ext_vector_type(8)));
typedef short s16x4 __attribute__((ext_vector_type(4)));
typedef float f32x4 __attribute__((ext_vector_type(4)));
typedef unsigned u32x2 __attribute__((ext_vector_type(2)));

static __device__ __forceinline__ unsigned short f2bf(float f) {
  unsigned u = __builtin_bit_cast(unsigned, f);
  u += 0x7fffu + ((u >> 16) & 1u);           // RNE
  return (unsigned short)(u >> 16);
}

static __device__ __forceinline__ unsigned cvt_pk_bf16(float lo, float hi) {
  unsigned r;
  asm("v_cvt_pk_bf16_f32 %0, %1, %2" : "=v"(r) : "v"(lo), "v"(hi));
  return r;
}

static __device__ __forceinline__ void gload_lds16(const void* g, void* l) {
  __builtin_amdgcn_global_load_lds((__attribute__((address_space(1))) void*)g,
                                   (__attribute__((address_space(3))) void*)l,
                                   16, 0, 0);
}

#define MFMA16(a, b, c) __builtin_amdgcn_mfma_f32_16x16x32_bf16(a, b, c, 0, 0, 0)

// ---------------- RoPE cos/sin table: [2048][32] each ----------------
__global__ void __launch_bounds__(256) rope_table(const int* __restrict__ pos,
                                                  float* __restrict__ ctab,
                                                  float* __restrict__ stab) {
  int g = blockIdx.x * 256 + threadIdx.x;     // 65536 total
  int s = g >> 5, i = g & 31;
  float p = (float)pos[s];
  float ang = p * exp2f(-(float)i * 0.41524101186092029f);
  ctab[g] = cosf(ang);
  stab[g] = sinf(ang);
}

// ---------------- fp32 -> bf16 convert (x8 vectorized) ----------------
__global__ void __launch_bounds__(256) cvt_f32_bf16(const float* __restrict__ src,
                                                    unsigned short* __restrict__ dst,
                                                    int n8) {
  int i = blockIdx.x * 256 + threadIdx.x;
  if (i >= n8) return;
  f32x4 a = ((const f32x4*)src)[i * 2];
  f32x4 b = ((const f32x4*)src)[i * 2 + 1];
  s16x8 o;
#pragma unroll
  for (int j = 0; j < 4; ++j) o[j] = (short)f2bf(a[j]);
#pragma unroll
  for (int j = 0; j < 4; ++j) o[4 + j] = (short)f2bf(b[j]);
  ((s16x8*)dst)[i] = o;
}

// all four weight matrices in one dispatch (grid.y selects)
__global__ void __launch_bounds__(256) cvt_weights(const float* __restrict__ w0,
                                                   const float* __restrict__ w1,
                                                   const float* __restrict__ w2,
                                                   const float* __restrict__ w3,
                                                   unsigned short* __restrict__ d0,
                                                   unsigned short* __restrict__ d1,
                                                   unsigned short* __restrict__ d2,
                                                   unsigned short* __restrict__ d3) {
  int which = blockIdx.y;
  const float* src = which == 0 ? w0 : which == 1 ? w1 : which == 2 ? w2 : w3;
  unsigned short* dst = which == 0 ? d0 : which == 1 ? d1 : which == 2 ? d2 : d3;
  int i = blockIdx.x * 256 + threadIdx.x;     // 131072 per matrix
  f32x4 a = ((const f32x4*)src)[i * 2];
  f32x4 b = ((const f32x4*)src)[i * 2 + 1];
  s16x8 o;
#pragma unroll
  for (int j = 0; j < 4; ++j) o[j] = (short)f2bf(a[j]);
#pragma unroll
  for (int j = 0; j < 4; ++j) o[4 + j] = (short)f2bf(b[j]);
  ((s16x8*)dst)[i] = o;
}

// ---------------- GEMM: C[M=8192][N=1024] = A[M][K] * B[N][K]^T --------------
// MODE 0: store f32 row-major (final Wo projection)
// MODE 1: RoPE epilogue, scale, store bf16 to [bh][s][64]   (Q and K)
// MODE 2: store bf16 transposed V^T [bh][d][s]              (V)
// XCD y-clustering remap: XCD k gets by in [8k, 8k+8) so all 8 bx-blocks of
// a row-panel share one L2 -> A-panel fetched once per y.
template<int MODE>
__global__ void __launch_bounds__(256) gemm_nt(const unsigned short* __restrict__ A,
                                               const unsigned short* __restrict__ B,
                                               void* __restrict__ dstv,
                                               const float* __restrict__ ctab,
                                               const float* __restrict__ stab,
                                               float scale) {
  __shared__ unsigned short ldsA[2][128 * 32];
  __shared__ unsigned short ldsB[2][128 * 32];
  const int tid = threadIdx.x;
  const int lane = tid & 63;
  const int wave = tid >> 6;
  const int wm = wave >> 1, wn = wave & 1;

  int flat = blockIdx.y * 8 + blockIdx.x;
  int logical = (flat & 7) * 64 + (flat >> 3);
  const int m0 = (logical >> 3) * 128;
  const int n0 = (logical & 7) * 128;
  const int l15 = lane & 15, lhi = lane >> 4;

  f32x4 acc[4][4] = {};

  auto stage = [&](int buf, int kt) {
    const int kbase = kt * 32;
#pragma unroll
    for (int issue = 0; issue < 2; ++issue) {
      int c = issue * 256 + wave * 64 + lane;   // chunk id 0..511
      int row = c >> 2, kc = c & 3;
      int kcg = kc ^ ((row >> 1) & 3);          // source chunk for this slot
      gload_lds16(A + (size_t)(m0 + row) * 1024 + kbase + kcg * 8,
                  &ldsA[buf][(issue * 256 + wave * 64) * 8]);
      gload_lds16(B + (size_t)(n0 + row) * 1024 + kbase + kcg * 8,
                  &ldsB[buf][(issue * 256 + wave * 64) * 8]);
    }
  };

  stage(0, 0);
  for (int kt = 0; kt < 32; ++kt) {
    __syncthreads();
    if (kt + 1 < 32) stage((kt + 1) & 1, kt + 1);
    const int buf = kt & 1;
    s16x8 af[4], bf[4];
#pragma unroll
    for (int mi = 0; mi < 4; ++mi) {
      int row = wm * 64 + mi * 16 + l15;
      int kc = lhi ^ ((row >> 1) & 3);
      af[mi] = *(const s16x8*)&ldsA[buf][row * 32 + kc * 8];
    }
#pragma unroll
    for (int ni = 0; ni < 4; ++ni) {
      int row = wn * 64 + ni * 16 + l15;
      int kc = lhi ^ ((row >> 1) & 3);
      bf[ni] = *(const s16x8*)&ldsB[buf][row * 32 + kc * 8];
    }
#pragma unroll
    for (int mi = 0; mi < 4; ++mi)
#pragma unroll
      for (int ni = 0; ni < 4; ++ni)
        acc[mi][ni] = MFMA16(af[mi], bf[ni], acc[mi][ni]);
  }

  // C layout: col = lane&15, row = (lane>>4)*4 + i
  if constexpr (MODE == 0) {
    float* dst = (float*)dstv;
#pragma unroll
    for (int mi = 0; mi < 4; ++mi)
#pragma unroll
      for (int ni = 0; ni < 4; ++ni)
#pragma unroll
        for (int i = 0; i < 4; ++i) {
          int r = m0 + wm * 64 + mi * 16 + lhi * 4 + i;
          int n = n0 + wn * 64 + ni * 16 + l15;
          dst[(size_t)r * 1024 + n] = acc[mi][ni][i];
        }
  } else if constexpr (MODE == 1) {
    unsigned short* dst = (unsigned short*)dstv;
#pragma unroll
    for (int mi = 0; mi < 4; ++mi)
#pragma unroll
      for (int ni = 0; ni < 4; ++ni)
#pragma unroll
        for (int i = 0; i < 4; ++i) {
          int r = m0 + wm * 64 + mi * 16 + lhi * 4 + i;
          int n = n0 + wn * 64 + ni * 16 + l15;
          float v = acc[mi][ni][i];
          float p = __shfl_xor(v, 1);           // RoPE partner
          int s = r & (SLEN - 1);
          int d = n & 63;
          int fi = d >> 1;
          float c = ctab[s * 32 + fi], sn = stab[s * 32 + fi];
          float o = (d & 1) ? (p * sn + v * c) : (v * c - p * sn);
          o *= scale;
          int b = r >> 11, h = n >> 6;
          dst[((size_t)(b * NHEADS + h) * SLEN + s) * 64 + d] = f2bf(o);
        }
  } else {  // MODE 2: V^T [bh][d][s]
    unsigned short* dst = (unsigned short*)dstv;
#pragma unroll
    for (int mi = 0; mi < 4; ++mi)
#pragma unroll
      for (int ni = 0; ni < 4; ++ni) {
        int r0 = m0 + wm * 64 + mi * 16 + lhi * 4;
        int n = n0 + wn * 64 + ni * 16 + l15;
        int b = r0 >> 11, s0 = r0 & (SLEN - 1);
        int h = n >> 6, d = n & 63;
        s16x4 pk;
#pragma unroll
        for (int i = 0; i < 4; ++i) pk[i] = (short)f2bf(acc[mi][ni][i]);
        *(s16x4*)&dst[((size_t)(b * NHEADS + h) * 64 + d) * SLEN + s0] = pk;
      }
  }
}

// ---------------- causal flash attention, v5 ----------------
// Q,K: [bh][s][64] bf16 (Q pre-scaled by 0.125*log2e), Vt: [bh][64][s] bf16.
// Round-3 skeleton: 1024 blocks x 128 threads (2 waves); block handles q-tile
// PAIR (t, 31-t) of 64 rows each -> uniform 33 k-tiles. Wave w owns 32 q-cols.
// NEW: V tiles ALSO staged via global_load_lds (dbuf) -> zero in-loop
// global->VGPR loads (compiler can't serialize what it never sees).
// Defer-rescale kept. LDS 40KB -> 4 blocks/CU = grid limit anyway.
__global__ void __launch_bounds__(128, 2) flash_attn(const unsigned short* __restrict__ Q,
                                                     const unsigned short* __restrict__ K,
                                                     const unsigned short* __restrict__ Vt,
                                                     unsigned short* __restrict__ Obf) {
  __shared__ unsigned short Kbuf[2][64 * 64];   // 16 KB, 16B-granule swizzle ^(row&7)
  __shared__ unsigned short Vbuf[2][64 * 64];   // 16 KB, same swizzle (rows = d)
  __shared__ unsigned short Pbuf[2][32 * 64];   // 8 KB, per-wave private

  const int tid = threadIdx.x, lane = tid & 63, w = tid >> 6;
  const int l15 = lane & 15, lhi = lane >> 4;
  const int swz = l15 & 7;

  // XCD chunking: XCD k gets bh in [8k, 8k+8)
  int id = blockIdx.x;                          // 1024 blocks
  int logical = (id & 7) * 128 + (id >> 3);
  const int bh = logical >> 4;                  // 0..63
  const int tp = logical & 15;                  // pair id 0..15
  const int b = bh >> 4, h = bh & 15;

  const unsigned short* Qb = Q + (size_t)bh * SLEN * 64;
  const unsigned short* Kb = K + (size_t)bh * SLEN * 64;
  const unsigned short* Vb = Vt + (size_t)bh * 64 * SLEN;

  // stage one 64x64 K tile AND one 64x64 Vt tile; sources pre-swizzled so
  // LDS stays linear for global_load_lds and ds_reads are conflict-free.
  auto stageKV = [&](int buf, int k0) {
#pragma unroll
    for (int j = 0; j < 4; ++j) {
      int c = j * 128 + tid;                    // 16B chunk 0..511
      int row = c >> 3, cg = c & 7;
      int col = ((cg ^ (row & 7)) * 8);
      gload_lds16(Kb + (size_t)(k0 + row) * 64 + col, &Kbuf[buf][c * 8]);
      gload_lds16(Vb + (size_t)row * SLEN + k0 + col, &Vbuf[buf][c * 8]);
    }
  };

  for (int half = 0; half < 2; ++half) {
    const int t = half ? (31 - tp) : tp;
    const int qbase = t * 64;
    const int nt = t + 1;

    // Q B-fragments: wave w owns q-cols [w*32, w*32+32)
    s16x8 qf[2][2];
#pragma unroll
    for (int nq = 0; nq < 2; ++nq)
#pragma unroll
      for (int kd = 0; kd < 2; ++kd)
        qf[nq][kd] = *(const s16x8*)&Qb[(size_t)(qbase + w * 32 + nq * 16 + l15) * 64 + kd * 32 + lhi * 8];

    f32x4 accT[4][2] = {};                      // O^T: row d, col q (lane-local q = l15)
    float m_run[2] = {-3.0e38f, -3.0e38f};
    float l_run[2] = {0.f, 0.f};

    stageKV(0, 0);
    for (int kt = 0; kt < nt; ++kt) {
      const int cur = kt & 1;
      __syncthreads();                          // vmcnt drain: stage(kt) landed; other buf free
      if (kt + 1 < nt) stageKV(cur ^ 1, (kt + 1) * 64);

      // K A-fragments from LDS (swizzled)
      s16x8 kf[4][2];
#pragma unroll
      for (int mk = 0; mk < 4; ++mk) {
        int r = mk * 16 + l15;
#pragma unroll
        for (int kd = 0; kd < 2; ++kd)
          kf[mk][kd] = *(const s16x8*)&Kbuf[cur][r * 64 + (((kd * 4 + lhi) ^ swz) * 8)];
      }

      // S^T = K * Q^T
      f32x4 sacc[4][2] = {};
#pragma unroll
      for (int mk = 0; mk < 4; ++mk)
#pragma unroll
        for (int nq = 0; nq < 2; ++nq) {
          sacc[mk][nq] = MFMA16(kf[mk][0], qf[nq][0], sacc[mk][nq]);
          sacc[mk][nq] = MFMA16(kf[mk][1], qf[nq][1], sacc[mk][nq]);
        }

      const bool diag = (kt == nt - 1);
#pragma unroll
      for (int nq = 0; nq < 2; ++nq) {
        const int qloc = w * 32 + nq * 16 + l15;
        if (diag) {
#pragma unroll
          for (int mk = 0; mk < 4; ++mk)
#pragma unroll
            for (int i = 0; i < 4; ++i)
              if (mk * 16 + lhi * 4 + i > qloc) sacc[mk][nq][i] = -3.0e38f;
        }
        float mx = sacc[0][nq][0];
#pragma unroll
        for (int mk = 0; mk < 4; ++mk)
#pragma unroll
          for (int i = 0; i < 4; ++i) mx = fmaxf(mx, sacc[mk][nq][i]);
        mx = fmaxf(mx, __shfl_xor(mx, 16));
        mx = fmaxf(mx, __shfl_xor(mx, 32));
        // defer-rescale: only rescale when the running max actually grows
        if (!__all(mx <= m_run[nq])) {
          const float mnew = fmaxf(m_run[nq], mx);
          const float facv = exp2f(m_run[nq] - mnew);
          m_run[nq] = mnew;
          l_run[nq] *= facv;
#pragma unroll
          for (int md = 0; md < 4; ++md)
#pragma unroll
            for (int i = 0; i < 4; ++i) accT[md][nq][i] *= facv;
        }
        float s0 = 0.f, s1 = 0.f;
#pragma unroll
        for (int mk = 0; mk < 4; ++mk) {
          f32x4 p;
#pragma unroll
          for (int i = 0; i < 4; ++i) p[i] = exp2f(sacc[mk][nq][i] - m_run[nq]);
          s0 += p[0] + p[1];
          s1 += p[2] + p[3];
          sacc[mk][nq] = p;
        }
        float sum = s0 + s1;
        sum += __shfl_xor(sum, 16);
        sum += __shfl_xor(sum, 32);
        l_run[nq] += sum;
      }

      // P -> bf16 -> private LDS [32 q][64 k], 16B-granule swizzle ^(q&7)
#pragma unroll
      for (int nq = 0; nq < 2; ++nq)
#pragma unroll
        for (int mk = 0; mk < 4; ++mk) {
          int q = nq * 16 + l15;
          int kog = mk * 2 + (lhi >> 1);
          int off = q * 64 + ((kog ^ swz) * 8) + (lhi & 1) * 4;
          u32x2 pk;
          pk[0] = cvt_pk_bf16(sacc[mk][nq][0], sacc[mk][nq][1]);
          pk[1] = cvt_pk_bf16(sacc[mk][nq][2], sacc[mk][nq][3]);
          *(u32x2*)&Pbuf[w][off] = pk;
        }

      // PV: O^T += Vt_frag (A, from LDS) * P^T (B, from LDS)
#pragma unroll
      for (int ks = 0; ks < 2; ++ks) {
        s16x8 pa[2];
#pragma unroll
        for (int nq = 0; nq < 2; ++nq) {
          int q = nq * 16 + l15;
          pa[nq] = *(const s16x8*)&Pbuf[w][q * 64 + (((ks * 4 + lhi) ^ swz) * 8)];
        }
        s16x8 vv[4];
#pragma unroll
        for (int md = 0; md < 4; ++md) {
          int r = md * 16 + l15;
          vv[md] = *(const s16x8*)&Vbuf[cur][r * 64 + (((ks * 4 + lhi) ^ swz) * 8)];
        }
#pragma unroll
        for (int md = 0; md < 4; ++md)
#pragma unroll
          for (int nq = 0; nq < 2; ++nq)
            accT[md][nq] = MFMA16(vv[md], pa[nq], accT[md][nq]);
      }
    }

    // normalize (lane-local) and store O^T -> [b][s][h*64+d]
#pragma unroll
    for (int nq = 0; nq < 2; ++nq) {
      float linv = 1.f / l_run[nq];
      int qg = qbase + w * 32 + nq * 16 + l15;
#pragma unroll
      for (int md = 0; md < 4; ++md) {
        u32x2 pk;
        pk[0] = cvt_pk_bf16(accT[md][nq][0] * linv, accT[md][nq][1] * linv);
        pk[1] = cvt_pk_bf16(accT[md][nq][2] * linv, accT[md][nq][3] * linv);
        *(u32x2*)&Obf[((size_t)(b * SLEN + qg)) * DMODEL + h * 64 + md * 16 + lhi * 4] = pk;
      }
    }
    __syncthreads();   // protect Kbuf/Vbuf before next half's prologue stage
  }
}

extern "C" void kernel_launch(void* const* d_in, const int* in_sizes, int n_in,
                              void* d_out, int out_size, void* d_ws, size_t ws_size,
                              hipStream_t stream) {
  const float* x  = (const float*)d_in[0];
  const float* Wq = (const float*)d_in[1];
  const float* Wk = (const float*)d_in[2];
  const float* Wv = (const float*)d_in[3];
  const float* Wo = (const float*)d_in[4];
  const int* pos  = (const int*)d_in[5];
  float* out = (float*)d_out;

  char* ws = (char*)d_ws;
  size_t off = 0;
  auto take = [&](size_t bytes) {
    char* p = ws + off;
    off += (bytes + 255) & ~(size_t)255;
    return p;
  };
  unsigned short* xbf  = (unsigned short*)take((size_t)MTOT * DMODEL * 2);
  unsigned short* wqbf = (unsigned short*)take((size_t)DMODEL * DMODEL * 2);
  unsigned short* wkbf = (unsigned short*)take((size_t)DMODEL * DMODEL * 2);
  unsigned short* wvbf = (unsigned short*)take((size_t)DMODEL * DMODEL * 2);
  unsigned short* wobf = (unsigned short*)take((size_t)DMODEL * DMODEL * 2);
  unsigned short* Qs   = (unsigned short*)take((size_t)64 * SLEN * 64 * 2);
  unsigned short* Ks   = (unsigned short*)take((size_t)64 * SLEN * 64 * 2);
  unsigned short* Vt   = (unsigned short*)take((size_t)64 * 64 * SLEN * 2);
  unsigned short* Obf  = (unsigned short*)take((size_t)MTOT * DMODEL * 2);
  float* ctab = (float*)take((size_t)SLEN * 32 * 4);
  float* stab = (float*)take((size_t)SLEN * 32 * 4);

  rope_table<<<256, 256, 0, stream>>>(pos, ctab, stab);
  cvt_f32_bf16<<<4096, 256, 0, stream>>>(x, xbf, MTOT * DMODEL / 8);
  cvt_weights<<<dim3(512, 4), 256, 0, stream>>>(Wq, Wk, Wv, Wo, wqbf, wkbf, wvbf, wobf);

  dim3 gg(DMODEL / 128, MTOT / 128);  // (8, 64)
  // Q: RoPE + fold softmax scale 0.125 * log2(e)
  gemm_nt<1><<<gg, 256, 0, stream>>>(xbf, wqbf, Qs, ctab, stab, 0.18033688011112042f);
  // K: RoPE only
  gemm_nt<1><<<gg, 256, 0, stream>>>(xbf, wkbf, Ks, ctab, stab, 1.0f);
  // V: transposed store
  gemm_nt<2><<<gg, 256, 0, stream>>>(xbf, wvbf, Vt, ctab, stab, 1.0f);

  flash_attn<<<1024, 128, 0, stream>>>(Qs, Ks, Vt, Obf);

  // final projection, fp32 output
  gemm_nt<0><<<gg, 256, 0, stream>>>(Obf, wobf, out, nullptr, nullptr, 1.0f);
}

// Round 7
// 221.497 us; speedup vs baseline: 1.1376x; 1.0296x over previous
//
#include <hip/hip_runtime.h>
#include <stdint.h>

#define SLEN 2048
#define DMODEL 1024
#define NHEADS 16
#define MTOT 8192   // 4 * 2048

typedef short s16x8 __attribute__((ext_vector_type(8)));
typedef short s16x4 __attribute__((ext_vector_type(4)));
typedef float f32x4 __attribute__((ext_vector_type(4)));
typedef float f32x16 __attribute__((ext_vector_type(16)));
typedef unsigned u32x2 __attribute__((ext_vector_type(2)));
typedef unsigned u32x4 __attribute__((ext_vector_type(4)));

static __device__ __forceinline__ unsigned short f2bf(float f) {
  unsigned u = __builtin_bit_cast(unsigned, f);
  u += 0x7fffu + ((u >> 16) & 1u);           // RNE
  return (unsigned short)(u >> 16);
}

static __device__ __forceinline__ unsigned cvt_pk_bf16(float lo, float hi) {
  unsigned r;
  asm("v_cvt_pk_bf16_f32 %0, %1, %2" : "=v"(r) : "v"(lo), "v"(hi));
  return r;
}

static __device__ __forceinline__ void gload_lds16(const void* g, void* l) {
  __builtin_amdgcn_global_load_lds((__attribute__((address_space(1))) void*)g,
                                   (__attribute__((address_space(3))) void*)l,
                                   16, 0, 0);
}

#define MFMA16(a, b, c) __builtin_amdgcn_mfma_f32_16x16x32_bf16(a, b, c, 0, 0, 0)
#define MFMA32(a, b, c) __builtin_amdgcn_mfma_f32_32x32x16_bf16(a, b, c, 0, 0, 0)

// ---------------- RoPE cos/sin table: [2048][32] each ----------------
__global__ void __launch_bounds__(256) rope_table(const int* __restrict__ pos,
                                                  float* __restrict__ ctab,
                                                  float* __restrict__ stab) {
  int g = blockIdx.x * 256 + threadIdx.x;     // 65536 total
  int s = g >> 5, i = g & 31;
  float p = (float)pos[s];
  float ang = p * exp2f(-(float)i * 0.41524101186092029f);
  ctab[g] = cosf(ang);
  stab[g] = sinf(ang);
}

// ---------------- fp32 -> bf16 convert (x8 vectorized) ----------------
__global__ void __launch_bounds__(256) cvt_f32_bf16(const float* __restrict__ src,
                                                    unsigned short* __restrict__ dst,
                                                    int n8) {
  int i = blockIdx.x * 256 + threadIdx.x;
  if (i >= n8) return;
  f32x4 a = ((const f32x4*)src)[i * 2];
  f32x4 b = ((const f32x4*)src)[i * 2 + 1];
  s16x8 o;
#pragma unroll
  for (int j = 0; j < 4; ++j) o[j] = (short)f2bf(a[j]);
#pragma unroll
  for (int j = 0; j < 4; ++j) o[4 + j] = (short)f2bf(b[j]);
  ((s16x8*)dst)[i] = o;
}

// all four weight matrices in one dispatch (grid.y selects)
__global__ void __launch_bounds__(256) cvt_weights(const float* __restrict__ w0,
                                                   const float* __restrict__ w1,
                                                   const float* __restrict__ w2,
                                                   const float* __restrict__ w3,
                                                   unsigned short* __restrict__ d0,
                                                   unsigned short* __restrict__ d1,
                                                   unsigned short* __restrict__ d2,
                                                   unsigned short* __restrict__ d3) {
  int which = blockIdx.y;
  const float* src = which == 0 ? w0 : which == 1 ? w1 : which == 2 ? w2 : w3;
  unsigned short* dst = which == 0 ? d0 : which == 1 ? d1 : which == 2 ? d2 : d3;
  int i = blockIdx.x * 256 + threadIdx.x;     // 131072 per matrix
  f32x4 a = ((const f32x4*)src)[i * 2];
  f32x4 b = ((const f32x4*)src)[i * 2 + 1];
  s16x8 o;
#pragma unroll
  for (int j = 0; j < 4; ++j) o[j] = (short)f2bf(a[j]);
#pragma unroll
  for (int j = 0; j < 4; ++j) o[4 + j] = (short)f2bf(b[j]);
  ((s16x8*)dst)[i] = o;
}

// ---------------- GEMM: C[M=8192][N=1024] = A[M][K] * B[N][K]^T --------------
// MODE 0: store f32 row-major (final Wo projection)
// MODE 1: RoPE epilogue, scale, store bf16 to [bh][s][64]   (Q and K)
// MODE 2: store bf16 transposed V^T [bh][d][s]              (V)
// XCD y-clustering remap: XCD k gets by in [8k, 8k+8) so all 8 bx-blocks of
// a row-panel share one L2 -> A-panel fetched once per y.
template<int MODE>
__global__ void __launch_bounds__(256) gemm_nt(const unsigned short* __restrict__ A,
                                               const unsigned short* __restrict__ B,
                                               void* __restrict__ dstv,
                                               const float* __restrict__ ctab,
                                               const float* __restrict__ stab,
                                               float scale) {
  __shared__ unsigned short ldsA[2][128 * 32];
  __shared__ unsigned short ldsB[2][128 * 32];
  const int tid = threadIdx.x;
  const int lane = tid & 63;
  const int wave = tid >> 6;
  const int wm = wave >> 1, wn = wave & 1;

  int flat = blockIdx.y * 8 + blockIdx.x;
  int logical = (flat & 7) * 64 + (flat >> 3);
  const int m0 = (logical >> 3) * 128;
  const int n0 = (logical & 7) * 128;
  const int l15 = lane & 15, lhi = lane >> 4;

  f32x4 acc[4][4] = {};

  auto stage = [&](int buf, int kt) {
    const int kbase = kt * 32;
#pragma unroll
    for (int issue = 0; issue < 2; ++issue) {
      int c = issue * 256 + wave * 64 + lane;   // chunk id 0..511
      int row = c >> 2, kc = c & 3;
      int kcg = kc ^ ((row >> 1) & 3);          // source chunk for this slot
      gload_lds16(A + (size_t)(m0 + row) * 1024 + kbase + kcg * 8,
                  &ldsA[buf][(issue * 256 + wave * 64) * 8]);
      gload_lds16(B + (size_t)(n0 + row) * 1024 + kbase + kcg * 8,
                  &ldsB[buf][(issue * 256 + wave * 64) * 8]);
    }
  };

  stage(0, 0);
  for (int kt = 0; kt < 32; ++kt) {
    __syncthreads();
    if (kt + 1 < 32) stage((kt + 1) & 1, kt + 1);
    const int buf = kt & 1;
    s16x8 af[4], bf[4];
#pragma unroll
    for (int mi = 0; mi < 4; ++mi) {
      int row = wm * 64 + mi * 16 + l15;
      int kc = lhi ^ ((row >> 1) & 3);
      af[mi] = *(const s16x8*)&ldsA[buf][row * 32 + kc * 8];
    }
#pragma unroll
    for (int ni = 0; ni < 4; ++ni) {
      int row = wn * 64 + ni * 16 + l15;
      int kc = lhi ^ ((row >> 1) & 3);
      bf[ni] = *(const s16x8*)&ldsB[buf][row * 32 + kc * 8];
    }
#pragma unroll
    for (int mi = 0; mi < 4; ++mi)
#pragma unroll
      for (int ni = 0; ni < 4; ++ni)
        acc[mi][ni] = MFMA16(af[mi], bf[ni], acc[mi][ni]);
  }

  // C layout: col = lane&15, row = (lane>>4)*4 + i
  if constexpr (MODE == 0) {
    float* dst = (float*)dstv;
#pragma unroll
    for (int mi = 0; mi < 4; ++mi)
#pragma unroll
      for (int ni = 0; ni < 4; ++ni)
#pragma unroll
        for (int i = 0; i < 4; ++i) {
          int r = m0 + wm * 64 + mi * 16 + lhi * 4 + i;
          int n = n0 + wn * 64 + ni * 16 + l15;
          dst[(size_t)r * 1024 + n] = acc[mi][ni][i];
        }
  } else if constexpr (MODE == 1) {
    unsigned short* dst = (unsigned short*)dstv;
#pragma unroll
    for (int mi = 0; mi < 4; ++mi)
#pragma unroll
      for (int ni = 0; ni < 4; ++ni)
#pragma unroll
        for (int i = 0; i < 4; ++i) {
          int r = m0 + wm * 64 + mi * 16 + lhi * 4 + i;
          int n = n0 + wn * 64 + ni * 16 + l15;
          float v = acc[mi][ni][i];
          float p = __shfl_xor(v, 1);           // RoPE partner
          int s = r & (SLEN - 1);
          int d = n & 63;
          int fi = d >> 1;
          float c = ctab[s * 32 + fi], sn = stab[s * 32 + fi];
          float o = (d & 1) ? (p * sn + v * c) : (v * c - p * sn);
          o *= scale;
          int b = r >> 11, h = n >> 6;
          dst[((size_t)(b * NHEADS + h) * SLEN + s) * 64 + d] = f2bf(o);
        }
  } else {  // MODE 2: V^T [bh][d][s]
    unsigned short* dst = (unsigned short*)dstv;
#pragma unroll
    for (int mi = 0; mi < 4; ++mi)
#pragma unroll
      for (int ni = 0; ni < 4; ++ni) {
        int r0 = m0 + wm * 64 + mi * 16 + lhi * 4;
        int n = n0 + wn * 64 + ni * 16 + l15;
        int b = r0 >> 11, s0 = r0 & (SLEN - 1);
        int h = n >> 6, d = n & 63;
        s16x4 pk;
#pragma unroll
        for (int i = 0; i < 4; ++i) pk[i] = (short)f2bf(acc[mi][ni][i]);
        *(s16x4*)&dst[((size_t)(b * NHEADS + h) * 64 + d) * SLEN + s0] = pk;
      }
  }
}

// ---------------- causal flash attention, v7: 32x32 swapped-QK ----------------
// Q,K: [bh][s][64] bf16 (Q pre-scaled by 0.125*log2e), Vt: [bh][64][s] bf16.
// 512 blocks x 256 threads (4 waves). Block = q-tile PAIR (t, 15-t) of 128
// rows -> uniform 34 k-tiles. Wave owns 32 q-cols. 2 blocks/CU.
// S^T = mfma32(K, Q): lane holds 32 k-values of ONE q-col -> softmax is
// lane-local + one shfl_xor(32). P repacked in-register (cvt_pk + shfl_xor)
// into PV B-frags -> no P LDS round-trip. O^T = mfma32(Vt, P): rescale and
// normalize lane-local. K/V staged via global_load_lds dbuf with COUNTED
// vmcnt (never 0 mid-loop) + raw s_barrier.
// v7 fix: mask condition uses the wave's MIN q (k0+63 > qbase+w*32), not max;
// v6 leaked unmasked k for waves whose q-range starts mid-tile (absmax 0.785).
__global__ void __launch_bounds__(256, 2) flash_attn(const unsigned short* __restrict__ Q,
                                                     const unsigned short* __restrict__ K,
                                                     const unsigned short* __restrict__ Vt,
                                                     unsigned short* __restrict__ Obf) {
  __shared__ unsigned short Kbuf[2][64 * 64];   // 8 KB each, 16B-granule swizzle ^(row&7)
  __shared__ unsigned short Vbuf[2][64 * 64];   // rows = d, cols = k-local

  const int tid = threadIdx.x, lane = tid & 63, w = tid >> 6;
  const int l31 = lane & 31, h = lane >> 5;     // h: which 32-lane half

  // XCD chunking: XCD k gets bh in [8k, 8k+8)
  int id = blockIdx.x;                          // 0..511
  int logical = (id & 7) * 64 + (id >> 3);
  const int bh = logical >> 3;                  // 0..63
  const int pr = logical & 7;                   // pair id 0..7
  const int b = bh >> 4, hd = bh & 15;

  const unsigned short* Qb = Q + (size_t)bh * SLEN * 64;
  const unsigned short* Kb = K + (size_t)bh * SLEN * 64;
  const unsigned short* Vb = Vt + (size_t)bh * 64 * SLEN;

  // stage one 64x64 K tile + one 64x64 Vt tile (16 KB = 16 instrs = 4/wave)
  auto stageKV = [&](int buf, int k0) {
#pragma unroll
    for (int i = 0; i < 2; ++i) {
      int c = i * 256 + tid;                    // 16B chunk 0..511
      int row = c >> 3, cg = c & 7;
      int col = ((cg ^ (row & 7)) * 8);
      gload_lds16(Kb + (size_t)(k0 + row) * 64 + col, &Kbuf[buf][c * 8]);
      gload_lds16(Vb + (size_t)row * SLEN + k0 + col, &Vbuf[buf][c * 8]);
    }
  };

  for (int half = 0; half < 2; ++half) {
    const int t = half ? (15 - pr) : pr;
    const int qbase = t * 128;
    const int nt = 2 * t + 2;                   // k-tiles (even)
    const int q_abs = qbase + w * 32 + l31;     // this lane's q column
    const int qminw = qbase + w * 32;           // wave's smallest q
    const int qmaxw = qminw + 31;

    // Q B-fragments: lane holds Q[q_abs][dc*16 + h*8 + j]
    s16x8 qf[4];
#pragma unroll
    for (int dc = 0; dc < 4; ++dc)
      qf[dc] = *(const s16x8*)&Qb[(size_t)q_abs * 64 + dc * 16 + h * 8];

    f32x16 accT[2] = {};                        // O^T: d = db*32+(r&3)+8*(r>>2)+4h, col q
    float m_run = -3.0e38f, l_run = 0.f;

    stageKV(0, 0);
    for (int kt = 0; kt < nt; ++kt) {
      const int cur = kt & 1;
      const int k0 = kt * 64;
      if (kt + 1 < nt) {
        stageKV(cur ^ 1, (kt + 1) * 64);
        asm volatile("s_waitcnt vmcnt(4)" ::: "memory");   // stage(kt) landed; (kt+1) in flight
      } else {
        asm volatile("s_waitcnt vmcnt(0)" ::: "memory");
      }
      __builtin_amdgcn_s_barrier();
      __builtin_amdgcn_sched_barrier(0);

      if (k0 <= qmaxw) {                        // tile not fully masked for this wave
        // S^T = K * Q^T : two 32-k blocks
        f32x16 sacc[2] = {};
#pragma unroll
        for (int kb = 0; kb < 2; ++kb) {
#pragma unroll
          for (int dc = 0; dc < 4; ++dc) {
            int r = kb * 32 + l31;
            int g = dc * 2 + h;
            s16x8 kf = *(const s16x8*)&Kbuf[cur][r * 64 + ((g ^ (r & 7)) * 8)];
            sacc[kb] = MFMA32(kf, qf[dc], sacc[kb]);
          }
        }

        // causal mask on the tile overlapping the wave's q range
        // (k row of element r = (r&3)+8*(r>>2)+4h)
        if (k0 + 63 > qminw) {
#pragma unroll
          for (int kb = 0; kb < 2; ++kb)
#pragma unroll
            for (int r = 0; r < 16; ++r) {
              int k_abs = k0 + kb * 32 + (r & 3) + 8 * (r >> 2) + 4 * h;
              if (k_abs > q_abs) sacc[kb][r] = -3.0e38f;
            }
        }

        // lane-local max over 32 k + one cross-half combine
        float mx = sacc[0][0];
#pragma unroll
        for (int kb = 0; kb < 2; ++kb)
#pragma unroll
          for (int r = 0; r < 16; ++r) mx = fmaxf(mx, sacc[kb][r]);
        mx = fmaxf(mx, __shfl_xor(mx, 32));

        if (!__all(mx <= m_run)) {              // defer-rescale
          float mnew = fmaxf(m_run, mx);
          float facv = exp2f(m_run - mnew);
          m_run = mnew;
          l_run *= facv;
#pragma unroll
          for (int db = 0; db < 2; ++db)
#pragma unroll
            for (int r = 0; r < 16; ++r) accT[db][r] *= facv;
        }

        // exp2 + lane-local sum + cross-half combine
        float sum = 0.f;
#pragma unroll
        for (int kb = 0; kb < 2; ++kb)
#pragma unroll
          for (int r = 0; r < 16; ++r) {
            float p = exp2f(sacc[kb][r] - m_run);
            sacc[kb][r] = p;
            sum += p;
          }
        l_run += sum + __shfl_xor(sum, 32);

        // pack P to bf16 PV B-frags in-register.
        // Holder u32s: H[u][i], u = kb*4+Q4 covers k = kb*32+8*Q4+4h + {0..3}.
        unsigned Hv[8][2];
#pragma unroll
        for (int kb = 0; kb < 2; ++kb)
#pragma unroll
          for (int q4 = 0; q4 < 4; ++q4) {
            Hv[kb * 4 + q4][0] = cvt_pk_bf16(sacc[kb][q4 * 4 + 0], sacc[kb][q4 * 4 + 1]);
            Hv[kb * 4 + q4][1] = cvt_pk_bf16(sacc[kb][q4 * 4 + 2], sacc[kb][q4 * 4 + 3]);
          }
        // Frag c needs k = c*16 + 8h + j (j=0..7): j0..3 from h'=0 holder,
        // j4..7 from h'=1 holder, both at u = 2c + h (this lane's h).
        s16x8 pf[4];
#pragma unroll
        for (int c = 0; c < 4; ++c) {
          unsigned loc0 = h ? Hv[2 * c + 1][0] : Hv[2 * c][0];
          unsigned loc1 = h ? Hv[2 * c + 1][1] : Hv[2 * c][1];
          unsigned snd0 = h ? Hv[2 * c][0] : Hv[2 * c + 1][0];
          unsigned snd1 = h ? Hv[2 * c][1] : Hv[2 * c + 1][1];
          unsigned rcv0 = (unsigned)__shfl_xor((int)snd0, 32);
          unsigned rcv1 = (unsigned)__shfl_xor((int)snd1, 32);
          u32x4 tv;
          tv[0] = h ? rcv0 : loc0;              // k j0..3  (h'=0 holder)
          tv[1] = h ? rcv1 : loc1;
          tv[2] = h ? loc0 : rcv0;              // k j4..7  (h'=1 holder)
          tv[3] = h ? loc1 : rcv1;
          pf[c] = __builtin_bit_cast(s16x8, tv);
        }

        // PV: O^T += Vt (A, LDS) * P (B, regs)
#pragma unroll
        for (int db = 0; db < 2; ++db)
#pragma unroll
          for (int kc = 0; kc < 4; ++kc) {
            int r = db * 32 + l31;
            int g = kc * 2 + h;
            s16x8 vf = *(const s16x8*)&Vbuf[cur][r * 64 + ((g ^ (r & 7)) * 8)];
            accT[db] = MFMA32(vf, pf[kc], accT[db]);
          }
      }

      __builtin_amdgcn_sched_barrier(0);
      __builtin_amdgcn_s_barrier();
    }

    // normalize (lane-local) and store O^T -> [b][s][h*64+d]
    float linv = 1.f / l_run;
#pragma unroll
    for (int db = 0; db < 2; ++db)
#pragma unroll
      for (int q4 = 0; q4 < 4; ++q4) {
        u32x2 pk;
        pk[0] = cvt_pk_bf16(accT[db][q4 * 4 + 0] * linv, accT[db][q4 * 4 + 1] * linv);
        pk[1] = cvt_pk_bf16(accT[db][q4 * 4 + 2] * linv, accT[db][q4 * 4 + 3] * linv);
        int d0 = db * 32 + 8 * q4 + 4 * h;
        *(u32x2*)&Obf[((size_t)(b * SLEN + q_abs)) * DMODEL + hd * 64 + d0] = pk;
      }
  }
}

extern "C" void kernel_launch(void* const* d_in, const int* in_sizes, int n_in,
                              void* d_out, int out_size, void* d_ws, size_t ws_size,
                              hipStream_t stream) {
  const float* x  = (const float*)d_in[0];
  const float* Wq = (const float*)d_in[1];
  const float* Wk = (const float*)d_in[2];
  const float* Wv = (const float*)d_in[3];
  const float* Wo = (const float*)d_in[4];
  const int* pos  = (const int*)d_in[5];
  float* out = (float*)d_out;

  char* ws = (char*)d_ws;
  size_t off = 0;
  auto take = [&](size_t bytes) {
    char* p = ws + off;
    off += (bytes + 255) & ~(size_t)255;
    return p;
  };
  unsigned short* xbf  = (unsigned short*)take((size_t)MTOT * DMODEL * 2);
  unsigned short* wqbf = (unsigned short*)take((size_t)DMODEL * DMODEL * 2);
  unsigned short* wkbf = (unsigned short*)take((size_t)DMODEL * DMODEL * 2);
  unsigned short* wvbf = (unsigned short*)take((size_t)DMODEL * DMODEL * 2);
  unsigned short* wobf = (unsigned short*)take((size_t)DMODEL * DMODEL * 2);
  unsigned short* Qs   = (unsigned short*)take((size_t)64 * SLEN * 64 * 2);
  unsigned short* Ks   = (unsigned short*)take((size_t)64 * SLEN * 64 * 2);
  unsigned short* Vt   = (unsigned short*)take((size_t)64 * 64 * SLEN * 2);
  unsigned short* Obf  = (unsigned short*)take((size_t)MTOT * DMODEL * 2);
  float* ctab = (float*)take((size_t)SLEN * 32 * 4);
  float* stab = (float*)take((size_t)SLEN * 32 * 4);

  rope_table<<<256, 256, 0, stream>>>(pos, ctab, stab);
  cvt_f32_bf16<<<4096, 256, 0, stream>>>(x, xbf, MTOT * DMODEL / 8);
  cvt_weights<<<dim3(512, 4), 256, 0, stream>>>(Wq, Wk, Wv, Wo, wqbf, wkbf, wvbf, wobf);

  dim3 gg(DMODEL / 128, MTOT / 128);  // (8, 64)
  // Q: RoPE + fold softmax scale 0.125 * log2(e)
  gemm_nt<1><<<gg, 256, 0, stream>>>(xbf, wqbf, Qs, ctab, stab, 0.18033688011112042f);
  // K: RoPE only
  gemm_nt<1><<<gg, 256, 0, stream>>>(xbf, wkbf, Ks, ctab, stab, 1.0f);
  // V: transposed store
  gemm_nt<2><<<gg, 256, 0, stream>>>(xbf, wvbf, Vt, ctab, stab, 1.0f);

  flash_attn<<<512, 256, 0, stream>>>(Qs, Ks, Vt, Obf);

  // final projection, fp32 output
  gemm_nt<0><<<gg, 256, 0, stream>>>(Obf, wobf, out, nullptr, nullptr, 1.0f);
}

// Round 8
// 202.254 us; speedup vs baseline: 1.2458x; 1.0951x over previous
//
#include <hip/hip_runtime.h>
#include <stdint.h>

#define SLEN 2048
#define DMODEL 1024
#define NHEADS 16
#define MTOT 8192   // 4 * 2048

typedef short s16x8 __attribute__((ext_vector_type(8)));
typedef short s16x4 __attribute__((ext_vector_type(4)));
typedef float f32x4 __attribute__((ext_vector_type(4)));
typedef float f32x16 __attribute__((ext_vector_type(16)));
typedef unsigned u32x2 __attribute__((ext_vector_type(2)));
typedef unsigned u32x4 __attribute__((ext_vector_type(4)));

static __device__ __forceinline__ unsigned short f2bf(float f) {
  unsigned u = __builtin_bit_cast(unsigned, f);
  u += 0x7fffu + ((u >> 16) & 1u);           // RNE
  return (unsigned short)(u >> 16);
}

static __device__ __forceinline__ unsigned cvt_pk_bf16(float lo, float hi) {
  unsigned r;
  asm("v_cvt_pk_bf16_f32 %0, %1, %2" : "=v"(r) : "v"(lo), "v"(hi));
  return r;
}

static __device__ __forceinline__ void gload_lds16(const void* g, void* l) {
  __builtin_amdgcn_global_load_lds((__attribute__((address_space(1))) void*)g,
                                   (__attribute__((address_space(3))) void*)l,
                                   16, 0, 0);
}

#define MFMA16(a, b, c) __builtin_amdgcn_mfma_f32_16x16x32_bf16(a, b, c, 0, 0, 0)
#define MFMA32(a, b, c) __builtin_amdgcn_mfma_f32_32x32x16_bf16(a, b, c, 0, 0, 0)
// full-rank row swizzle: rows r, r+8, r+16, ... get distinct granule perms
#define SWZ(r) ((((r) & 7) ^ (((r) >> 3) & 7)))

// ---------------- RoPE cos/sin table: [2048][32] each ----------------
__global__ void __launch_bounds__(256) rope_table(const int* __restrict__ pos,
                                                  float* __restrict__ ctab,
                                                  float* __restrict__ stab) {
  int g = blockIdx.x * 256 + threadIdx.x;     // 65536 total
  int s = g >> 5, i = g & 31;
  float p = (float)pos[s];
  float ang = p * exp2f(-(float)i * 0.41524101186092029f);
  ctab[g] = cosf(ang);
  stab[g] = sinf(ang);
}

// ---------------- fp32 -> bf16 convert (x8 vectorized) ----------------
__global__ void __launch_bounds__(256) cvt_f32_bf16(const float* __restrict__ src,
                                                    unsigned short* __restrict__ dst,
                                                    int n8) {
  int i = blockIdx.x * 256 + threadIdx.x;
  if (i >= n8) return;
  f32x4 a = ((const f32x4*)src)[i * 2];
  f32x4 b = ((const f32x4*)src)[i * 2 + 1];
  s16x8 o;
#pragma unroll
  for (int j = 0; j < 4; ++j) o[j] = (short)f2bf(a[j]);
#pragma unroll
  for (int j = 0; j < 4; ++j) o[4 + j] = (short)f2bf(b[j]);
  ((s16x8*)dst)[i] = o;
}

// all four weight matrices in one dispatch (grid.y selects)
__global__ void __launch_bounds__(256) cvt_weights(const float* __restrict__ w0,
                                                   const float* __restrict__ w1,
                                                   const float* __restrict__ w2,
                                                   const float* __restrict__ w3,
                                                   unsigned short* __restrict__ d0,
                                                   unsigned short* __restrict__ d1,
                                                   unsigned short* __restrict__ d2,
                                                   unsigned short* __restrict__ d3) {
  int which = blockIdx.y;
  const float* src = which == 0 ? w0 : which == 1 ? w1 : which == 2 ? w2 : w3;
  unsigned short* dst = which == 0 ? d0 : which == 1 ? d1 : which == 2 ? d2 : d3;
  int i = blockIdx.x * 256 + threadIdx.x;     // 131072 per matrix
  f32x4 a = ((const f32x4*)src)[i * 2];
  f32x4 b = ((const f32x4*)src)[i * 2 + 1];
  s16x8 o;
#pragma unroll
  for (int j = 0; j < 4; ++j) o[j] = (short)f2bf(a[j]);
#pragma unroll
  for (int j = 0; j < 4; ++j) o[4 + j] = (short)f2bf(b[j]);
  ((s16x8*)dst)[i] = o;
}

// ---------------- GEMM: C[M=8192][N] = A[M][K=1024] * B[N][K]^T --------------
// MODE 0: N=1024, store f32 row-major (final Wo projection)
// MODE 3: N=3072 fused QKV against concatenated W_qkv. Per 128-col block:
//         n0>>10 == 0 -> Q (RoPE + scale), 1 -> K (RoPE), 2 -> V^T store.
// XCD clustering: XCD k owns a contiguous m-panel range so row-panels of A
// stay hot in that XCD's L2 across all n-blocks.
template<int MODE>
__global__ void __launch_bounds__(256) gemm_nt(const unsigned short* __restrict__ A,
                                               const unsigned short* __restrict__ B,
                                               void* __restrict__ dstQ,
                                               void* __restrict__ dstK,
                                               void* __restrict__ dstV,
                                               const float* __restrict__ ctab,
                                               const float* __restrict__ stab,
                                               float scale) {
  __shared__ unsigned short ldsA[2][128 * 32];
  __shared__ unsigned short ldsB[2][128 * 32];
  const int tid = threadIdx.x;
  const int lane = tid & 63;
  const int wave = tid >> 6;
  const int wm = wave >> 1, wn = wave & 1;

  int m0, n0;
  if constexpr (MODE == 3) {
    int flat = blockIdx.y * 24 + blockIdx.x;    // 1536 blocks
    int xcd = flat & 7, idx = flat >> 3;        // idx 0..191
    int lm = idx / 24, ln = idx - lm * 24;
    m0 = (xcd * 8 + lm) * 128;
    n0 = ln * 128;
  } else {
    int flat = blockIdx.y * 8 + blockIdx.x;     // 512 blocks
    int logical = (flat & 7) * 64 + (flat >> 3);
    m0 = (logical >> 3) * 128;
    n0 = (logical & 7) * 128;
  }
  const int l15 = lane & 15, lhi = lane >> 4;

  f32x4 acc[4][4] = {};

  auto stage = [&](int buf, int kt) {
    const int kbase = kt * 32;
#pragma unroll
    for (int issue = 0; issue < 2; ++issue) {
      int c = issue * 256 + wave * 64 + lane;   // chunk id 0..511
      int row = c >> 2, kc = c & 3;
      int kcg = kc ^ ((row >> 1) & 3);          // source chunk for this slot
      gload_lds16(A + (size_t)(m0 + row) * 1024 + kbase + kcg * 8,
                  &ldsA[buf][(issue * 256 + wave * 64) * 8]);
      gload_lds16(B + (size_t)(n0 + row) * 1024 + kbase + kcg * 8,
                  &ldsB[buf][(issue * 256 + wave * 64) * 8]);
    }
  };

  stage(0, 0);
  for (int kt = 0; kt < 32; ++kt) {
    __syncthreads();
    if (kt + 1 < 32) stage((kt + 1) & 1, kt + 1);
    const int buf = kt & 1;
    s16x8 af[4], bf[4];
#pragma unroll
    for (int mi = 0; mi < 4; ++mi) {
      int row = wm * 64 + mi * 16 + l15;
      int kc = lhi ^ ((row >> 1) & 3);
      af[mi] = *(const s16x8*)&ldsA[buf][row * 32 + kc * 8];
    }
#pragma unroll
    for (int ni = 0; ni < 4; ++ni) {
      int row = wn * 64 + ni * 16 + l15;
      int kc = lhi ^ ((row >> 1) & 3);
      bf[ni] = *(const s16x8*)&ldsB[buf][row * 32 + kc * 8];
    }
#pragma unroll
    for (int mi = 0; mi < 4; ++mi)
#pragma unroll
      for (int ni = 0; ni < 4; ++ni)
        acc[mi][ni] = MFMA16(af[mi], bf[ni], acc[mi][ni]);
  }

  // C layout: col = lane&15, row = (lane>>4)*4 + i
  if constexpr (MODE == 0) {
    float* dst = (float*)dstQ;
#pragma unroll
    for (int mi = 0; mi < 4; ++mi)
#pragma unroll
      for (int ni = 0; ni < 4; ++ni)
#pragma unroll
        for (int i = 0; i < 4; ++i) {
          int r = m0 + wm * 64 + mi * 16 + lhi * 4 + i;
          int n = n0 + wn * 64 + ni * 16 + l15;
          dst[(size_t)r * 1024 + n] = acc[mi][ni][i];
        }
  } else {  // MODE 3: fused QKV epilogue
    const int which = n0 >> 10;                 // 0=Q 1=K 2=V (uniform per block)
    if (which < 2) {
      unsigned short* dst = (unsigned short*)(which == 0 ? dstQ : dstK);
      const float sc = (which == 0) ? scale : 1.0f;
#pragma unroll
      for (int mi = 0; mi < 4; ++mi)
#pragma unroll
        for (int ni = 0; ni < 4; ++ni)
#pragma unroll
          for (int i = 0; i < 4; ++i) {
            int r = m0 + wm * 64 + mi * 16 + lhi * 4 + i;
            int nn = (n0 & 1023) + wn * 64 + ni * 16 + l15;
            float v = acc[mi][ni][i];
            float p = __shfl_xor(v, 1);         // RoPE partner
            int s = r & (SLEN - 1);
            int d = nn & 63;
            int fi = d >> 1;
            float c = ctab[s * 32 + fi], sn = stab[s * 32 + fi];
            float o = (d & 1) ? (p * sn + v * c) : (v * c - p * sn);
            o *= sc;
            int b = r >> 11, h = nn >> 6;
            dst[((size_t)(b * NHEADS + h) * SLEN + s) * 64 + d] = f2bf(o);
          }
    } else {  // V^T [bh][d][s]
      unsigned short* dst = (unsigned short*)dstV;
#pragma unroll
      for (int mi = 0; mi < 4; ++mi)
#pragma unroll
        for (int ni = 0; ni < 4; ++ni) {
          int r0 = m0 + wm * 64 + mi * 16 + lhi * 4;
          int nn = (n0 & 1023) + wn * 64 + ni * 16 + l15;
          int b = r0 >> 11, s0 = r0 & (SLEN - 1);
          int h = nn >> 6, d = nn & 63;
          s16x4 pk;
#pragma unroll
          for (int i = 0; i < 4; ++i) pk[i] = (short)f2bf(acc[mi][ni][i]);
          *(s16x4*)&dst[((size_t)(b * NHEADS + h) * 64 + d) * SLEN + s0] = pk;
        }
    }
  }
}

// ---------------- causal flash attention, v8: 32x32 swapped-QK ----------------
// Q,K: [bh][s][64] bf16 (Q pre-scaled by 0.125*log2e), Vt: [bh][64][s] bf16.
// 1024 blocks x 256 threads (4 waves), UNPAIRED, strict LPT dispatch order
// (t=15 blocks first). 4 blocks/CU (128KB LDS) -> 4 independent waves/SIMD.
// Inner loop identical to v7 except full-rank swizzle SWZ(r) = (r&7)^((r>>3)&7)
// so all 64 lanes of a b128 read hit distinct bank groups (v7: 8-way conflict).
__global__ void __launch_bounds__(256, 4) flash_attn(const unsigned short* __restrict__ Q,
                                                     const unsigned short* __restrict__ K,
                                                     const unsigned short* __restrict__ Vt,
                                                     unsigned short* __restrict__ Obf) {
  __shared__ unsigned short Kbuf[2][64 * 64];   // 8 KB each
  __shared__ unsigned short Vbuf[2][64 * 64];   // rows = d, cols = k-local

  const int tid = threadIdx.x, lane = tid & 63, w = tid >> 6;
  const int l31 = lane & 31, h = lane >> 5;     // h: which 32-lane half

  // XCD chunking by bh + LPT (t descending in dispatch order)
  int id = blockIdx.x;                          // 0..1023
  int xcd = id & 7, idx = id >> 3;              // idx 0..127
  const int bh = xcd * 8 + (idx & 7);           // XCD k owns bh [8k, 8k+8)
  const int t = 15 - (idx >> 3);                // big q-tiles dispatched first
  const int b = bh >> 4, hd = bh & 15;

  const unsigned short* Qb = Q + (size_t)bh * SLEN * 64;
  const unsigned short* Kb = K + (size_t)bh * SLEN * 64;
  const unsigned short* Vb = Vt + (size_t)bh * 64 * SLEN;

  const int qbase = t * 128;
  const int nt = 2 * t + 2;                     // k-tiles incl. diagonal
  const int q_abs = qbase + w * 32 + l31;       // this lane's q column
  const int qminw = qbase + w * 32;             // wave's smallest q

  // stage one 64x64 K tile + one 64x64 Vt tile (16 instrs = 4/wave)
  auto stageKV = [&](int buf, int k0) {
#pragma unroll
    for (int i = 0; i < 2; ++i) {
      int c = i * 256 + tid;                    // 16B chunk 0..511
      int row = c >> 3, cg = c & 7;
      int col = ((cg ^ SWZ(row)) * 8);
      gload_lds16(Kb + (size_t)(k0 + row) * 64 + col, &Kbuf[buf][c * 8]);
      gload_lds16(Vb + (size_t)row * SLEN + k0 + col, &Vbuf[buf][c * 8]);
    }
  };

  // Q B-fragments: lane holds Q[q_abs][dc*16 + h*8 + j]
  s16x8 qf[4];
#pragma unroll
  for (int dc = 0; dc < 4; ++dc)
    qf[dc] = *(const s16x8*)&Qb[(size_t)q_abs * 64 + dc * 16 + h * 8];

  f32x16 accT[2] = {};                          // O^T: d = db*32+(r&3)+8*(r>>2)+4h
  float m_run = -3.0e38f, l_run = 0.f;

  stageKV(0, 0);
  for (int kt = 0; kt < nt; ++kt) {
    const int cur = kt & 1;
    const int k0 = kt * 64;
    if (kt + 1 < nt) {
      stageKV(cur ^ 1, (kt + 1) * 64);
      asm volatile("s_waitcnt vmcnt(4)" ::: "memory");   // stage(kt) landed; (kt+1) in flight
    } else {
      asm volatile("s_waitcnt vmcnt(0)" ::: "memory");
    }
    __builtin_amdgcn_s_barrier();
    __builtin_amdgcn_sched_barrier(0);

    {
      // S^T = K * Q^T : two 32-k blocks
      f32x16 sacc[2] = {};
#pragma unroll
      for (int kb = 0; kb < 2; ++kb) {
#pragma unroll
        for (int dc = 0; dc < 4; ++dc) {
          int r = kb * 32 + l31;
          int g = dc * 2 + h;
          s16x8 kf = *(const s16x8*)&Kbuf[cur][r * 64 + ((g ^ SWZ(r)) * 8)];
          sacc[kb] = MFMA32(kf, qf[dc], sacc[kb]);
        }
      }

      // causal mask on tiles overlapping the wave's q range
      // (k row of element r = (r&3)+8*(r>>2)+4h)
      if (k0 + 63 > qminw) {
#pragma unroll
        for (int kb = 0; kb < 2; ++kb)
#pragma unroll
          for (int r = 0; r < 16; ++r) {
            int k_abs = k0 + kb * 32 + (r & 3) + 8 * (r >> 2) + 4 * h;
            if (k_abs > q_abs) sacc[kb][r] = -3.0e38f;
          }
      }

      // lane-local max over 32 k + one cross-half combine
      float mx = sacc[0][0];
#pragma unroll
      for (int kb = 0; kb < 2; ++kb)
#pragma unroll
        for (int r = 0; r < 16; ++r) mx = fmaxf(mx, sacc[kb][r]);
      mx = fmaxf(mx, __shfl_xor(mx, 32));

      if (!__all(mx <= m_run)) {                // defer-rescale
        float mnew = fmaxf(m_run, mx);
        float facv = exp2f(m_run - mnew);
        m_run = mnew;
        l_run *= facv;
#pragma unroll
        for (int db = 0; db < 2; ++db)
#pragma unroll
          for (int r = 0; r < 16; ++r) accT[db][r] *= facv;
      }

      // exp2 + lane-local sum + cross-half combine
      float sum = 0.f;
#pragma unroll
      for (int kb = 0; kb < 2; ++kb)
#pragma unroll
        for (int r = 0; r < 16; ++r) {
          float p = exp2f(sacc[kb][r] - m_run);
          sacc[kb][r] = p;
          sum += p;
        }
      l_run += sum + __shfl_xor(sum, 32);

      // pack P to bf16 PV B-frags in-register.
      // Holder u32s: H[u][i], u = kb*4+q4 covers k = kb*32+8*q4+4h + {0..3}.
      unsigned Hv[8][2];
#pragma unroll
      for (int kb = 0; kb < 2; ++kb)
#pragma unroll
        for (int q4 = 0; q4 < 4; ++q4) {
          Hv[kb * 4 + q4][0] = cvt_pk_bf16(sacc[kb][q4 * 4 + 0], sacc[kb][q4 * 4 + 1]);
          Hv[kb * 4 + q4][1] = cvt_pk_bf16(sacc[kb][q4 * 4 + 2], sacc[kb][q4 * 4 + 3]);
        }
      // Frag c needs k = c*16 + 8h + j (j=0..7): j0..3 from h'=0 holder,
      // j4..7 from h'=1 holder, both at u = 2c + h (this lane's h).
      s16x8 pf[4];
#pragma unroll
      for (int c = 0; c < 4; ++c) {
        unsigned loc0 = h ? Hv[2 * c + 1][0] : Hv[2 * c][0];
        unsigned loc1 = h ? Hv[2 * c + 1][1] : Hv[2 * c][1];
        unsigned snd0 = h ? Hv[2 * c][0] : Hv[2 * c + 1][0];
        unsigned snd1 = h ? Hv[2 * c][1] : Hv[2 * c + 1][1];
        unsigned rcv0 = (unsigned)__shfl_xor((int)snd0, 32);
        unsigned rcv1 = (unsigned)__shfl_xor((int)snd1, 32);
        u32x4 tv;
        tv[0] = h ? rcv0 : loc0;                // k j0..3  (h'=0 holder)
        tv[1] = h ? rcv1 : loc1;
        tv[2] = h ? loc0 : rcv0;                // k j4..7  (h'=1 holder)
        tv[3] = h ? loc1 : rcv1;
        pf[c] = __builtin_bit_cast(s16x8, tv);
      }

      // PV: O^T += Vt (A, LDS) * P (B, regs)
#pragma unroll
      for (int db = 0; db < 2; ++db)
#pragma unroll
        for (int kc = 0; kc < 4; ++kc) {
          int r = db * 32 + l31;
          int g = kc * 2 + h;
          s16x8 vf = *(const s16x8*)&Vbuf[cur][r * 64 + ((g ^ SWZ(r)) * 8)];
          accT[db] = MFMA32(vf, pf[kc], accT[db]);
        }
    }

    __builtin_amdgcn_sched_barrier(0);
    __builtin_amdgcn_s_barrier();
  }

  // normalize (lane-local) and store O^T -> [b][s][h*64+d]
  float linv = 1.f / l_run;
#pragma unroll
  for (int db = 0; db < 2; ++db)
#pragma unroll
    for (int q4 = 0; q4 < 4; ++q4) {
      u32x2 pk;
      pk[0] = cvt_pk_bf16(accT[db][q4 * 4 + 0] * linv, accT[db][q4 * 4 + 1] * linv);
      pk[1] = cvt_pk_bf16(accT[db][q4 * 4 + 2] * linv, accT[db][q4 * 4 + 3] * linv);
      int d0 = db * 32 + 8 * q4 + 4 * h;
      *(u32x2*)&Obf[((size_t)(b * SLEN + q_abs)) * DMODEL + hd * 64 + d0] = pk;
    }
}

extern "C" void kernel_launch(void* const* d_in, const int* in_sizes, int n_in,
                              void* d_out, int out_size, void* d_ws, size_t ws_size,
                              hipStream_t stream) {
  const float* x  = (const float*)d_in[0];
  const float* Wq = (const float*)d_in[1];
  const float* Wk = (const float*)d_in[2];
  const float* Wv = (const float*)d_in[3];
  const float* Wo = (const float*)d_in[4];
  const int* pos  = (const int*)d_in[5];
  float* out = (float*)d_out;

  char* ws = (char*)d_ws;
  size_t off = 0;
  auto take = [&](size_t bytes) {
    char* p = ws + off;
    off += (bytes + 255) & ~(size_t)255;
    return p;
  };
  unsigned short* xbf  = (unsigned short*)take((size_t)MTOT * DMODEL * 2);
  unsigned short* wqkv = (unsigned short*)take((size_t)3 * DMODEL * DMODEL * 2);
  unsigned short* wobf = (unsigned short*)take((size_t)DMODEL * DMODEL * 2);
  unsigned short* Qs   = (unsigned short*)take((size_t)64 * SLEN * 64 * 2);
  unsigned short* Ks   = (unsigned short*)take((size_t)64 * SLEN * 64 * 2);
  unsigned short* Vt   = (unsigned short*)take((size_t)64 * 64 * SLEN * 2);
  unsigned short* Obf  = (unsigned short*)take((size_t)MTOT * DMODEL * 2);
  float* ctab = (float*)take((size_t)SLEN * 32 * 4);
  float* stab = (float*)take((size_t)SLEN * 32 * 4);

  rope_table<<<256, 256, 0, stream>>>(pos, ctab, stab);
  cvt_f32_bf16<<<4096, 256, 0, stream>>>(x, xbf, MTOT * DMODEL / 8);
  // Wq, Wk, Wv land contiguously as W_qkv[3072][1024]; Wo separate.
  cvt_weights<<<dim3(512, 4), 256, 0, stream>>>(
      Wq, Wk, Wv, Wo,
      wqkv, wqkv + (size_t)DMODEL * DMODEL, wqkv + (size_t)2 * DMODEL * DMODEL, wobf);

  // fused QKV projection: C[8192][3072], epilogue routes per 128-col block
  gemm_nt<3><<<dim3(24, 64), 256, 0, stream>>>(xbf, wqkv, Qs, Ks, Vt,
                                               ctab, stab, 0.18033688011112042f);

  flash_attn<<<1024, 256, 0, stream>>>(Qs, Ks, Vt, Obf);

  // final projection, fp32 output
  gemm_nt<0><<<dim3(8, 64), 256, 0, stream>>>(Obf, wobf, out, nullptr, nullptr,
                                              nullptr, nullptr, 1.0f);
}

// Round 9
// 200.818 us; speedup vs baseline: 1.2547x; 1.0072x over previous
//
#include <hip/hip_runtime.h>
#include <stdint.h>

#define SLEN 2048
#define DMODEL 1024
#define NHEADS 16
#define MTOT 8192   // 4 * 2048

typedef short s16x8 __attribute__((ext_vector_type(8)));
typedef short s16x4 __attribute__((ext_vector_type(4)));
typedef float f32x4 __attribute__((ext_vector_type(4)));
typedef float f32x16 __attribute__((ext_vector_type(16)));
typedef unsigned u32x2 __attribute__((ext_vector_type(2)));
typedef unsigned u32x4 __attribute__((ext_vector_type(4)));

static __device__ __forceinline__ unsigned short f2bf(float f) {
  unsigned u = __builtin_bit_cast(unsigned, f);
  u += 0x7fffu + ((u >> 16) & 1u);           // RNE
  return (unsigned short)(u >> 16);
}

static __device__ __forceinline__ unsigned cvt_pk_bf16(float lo, float hi) {
  unsigned r;
  asm("v_cvt_pk_bf16_f32 %0, %1, %2" : "=v"(r) : "v"(lo), "v"(hi));
  return r;
}

static __device__ __forceinline__ void gload_lds16(const void* g, void* l) {
  __builtin_amdgcn_global_load_lds((__attribute__((address_space(1))) void*)g,
                                   (__attribute__((address_space(3))) void*)l,
                                   16, 0, 0);
}

#define MFMA16(a, b, c) __builtin_amdgcn_mfma_f32_16x16x32_bf16(a, b, c, 0, 0, 0)
#define MFMA32(a, b, c) __builtin_amdgcn_mfma_f32_32x32x16_bf16(a, b, c, 0, 0, 0)
// full-rank row swizzle: rows r, r+8, r+16, ... get distinct granule perms
#define SWZ(r) ((((r) & 7) ^ (((r) >> 3) & 7)))

// ---------------- RoPE cos/sin table: [2048][32] each ----------------
__global__ void __launch_bounds__(256) rope_table(const int* __restrict__ pos,
                                                  float* __restrict__ ctab,
                                                  float* __restrict__ stab) {
  int g = blockIdx.x * 256 + threadIdx.x;     // 65536 total
  int s = g >> 5, i = g & 31;
  float p = (float)pos[s];
  float ang = p * exp2f(-(float)i * 0.41524101186092029f);
  ctab[g] = cosf(ang);
  stab[g] = sinf(ang);
}

// ---------------- fp32 -> bf16 convert (x8 vectorized) ----------------
__global__ void __launch_bounds__(256) cvt_f32_bf16(const float* __restrict__ src,
                                                    unsigned short* __restrict__ dst,
                                                    int n8) {
  int i = blockIdx.x * 256 + threadIdx.x;
  if (i >= n8) return;
  f32x4 a = ((const f32x4*)src)[i * 2];
  f32x4 b = ((const f32x4*)src)[i * 2 + 1];
  s16x8 o;
#pragma unroll
  for (int j = 0; j < 4; ++j) o[j] = (short)f2bf(a[j]);
#pragma unroll
  for (int j = 0; j < 4; ++j) o[4 + j] = (short)f2bf(b[j]);
  ((s16x8*)dst)[i] = o;
}

// all four weight matrices in one dispatch (grid.y selects)
__global__ void __launch_bounds__(256) cvt_weights(const float* __restrict__ w0,
                                                   const float* __restrict__ w1,
                                                   const float* __restrict__ w2,
                                                   const float* __restrict__ w3,
                                                   unsigned short* __restrict__ d0,
                                                   unsigned short* __restrict__ d1,
                                                   unsigned short* __restrict__ d2,
                                                   unsigned short* __restrict__ d3) {
  int which = blockIdx.y;
  const float* src = which == 0 ? w0 : which == 1 ? w1 : which == 2 ? w2 : w3;
  unsigned short* dst = which == 0 ? d0 : which == 1 ? d1 : which == 2 ? d2 : d3;
  int i = blockIdx.x * 256 + threadIdx.x;     // 131072 per matrix
  f32x4 a = ((const f32x4*)src)[i * 2];
  f32x4 b = ((const f32x4*)src)[i * 2 + 1];
  s16x8 o;
#pragma unroll
  for (int j = 0; j < 4; ++j) o[j] = (short)f2bf(a[j]);
#pragma unroll
  for (int j = 0; j < 4; ++j) o[4 + j] = (short)f2bf(b[j]);
  ((s16x8*)dst)[i] = o;
}

// ---------------- GEMM: C[M=8192][N] = A[M][K=1024] * B[N][K]^T --------------
// MODE 0: N=1024, store f32 row-major (final Wo projection)
// MODE 3: N=3072 fused QKV against concatenated W_qkv. Per 128-col block:
//         n0>>10 == 0 -> Q (RoPE + scale), 1 -> K (RoPE), 2 -> V^T store.
// XCD mapping (both modes): per-XCD working set <= A 2MB + B 2MB = 4MB L2.
// MODE 3 iterates n in 3 GROUPS of 8 blocks (v8's lm-major order kept all
// 24 n-blocks co-resident -> B 6MB thrashed L2 -> every stage missed to L3).
template<int MODE>
__global__ void __launch_bounds__(256) gemm_nt(const unsigned short* __restrict__ A,
                                               const unsigned short* __restrict__ B,
                                               void* __restrict__ dstQ,
                                               void* __restrict__ dstK,
                                               void* __restrict__ dstV,
                                               const float* __restrict__ ctab,
                                               const float* __restrict__ stab,
                                               float scale) {
  __shared__ unsigned short ldsA[2][128 * 32];
  __shared__ unsigned short ldsB[2][128 * 32];
  const int tid = threadIdx.x;
  const int lane = tid & 63;
  const int wave = tid >> 6;
  const int wm = wave >> 1, wn = wave & 1;

  int m0, n0;
  if constexpr (MODE == 3) {
    int flat = blockIdx.y * 24 + blockIdx.x;    // 1536 blocks
    int xcd = flat & 7, idx = flat >> 3;        // idx 0..191 (per-XCD issue order)
    int g = idx >> 6;                           // n-group 0..2 (8 n-blocks each)
    int local = idx & 63;
    int lm = local >> 3, ln = local & 7;
    m0 = (xcd * 8 + lm) * 128;
    n0 = (g * 8 + ln) * 128;
  } else {
    int flat = blockIdx.y * 8 + blockIdx.x;     // 512 blocks
    int logical = (flat & 7) * 64 + (flat >> 3);
    m0 = (logical >> 3) * 128;
    n0 = (logical & 7) * 128;
  }
  const int l15 = lane & 15, lhi = lane >> 4;

  f32x4 acc[4][4] = {};

  auto stage = [&](int buf, int kt) {
    const int kbase = kt * 32;
#pragma unroll
    for (int issue = 0; issue < 2; ++issue) {
      int c = issue * 256 + wave * 64 + lane;   // chunk id 0..511
      int row = c >> 2, kc = c & 3;
      int kcg = kc ^ ((row >> 1) & 3);          // source chunk for this slot
      gload_lds16(A + (size_t)(m0 + row) * 1024 + kbase + kcg * 8,
                  &ldsA[buf][(issue * 256 + wave * 64) * 8]);
      gload_lds16(B + (size_t)(n0 + row) * 1024 + kbase + kcg * 8,
                  &ldsB[buf][(issue * 256 + wave * 64) * 8]);
    }
  };

  stage(0, 0);
  for (int kt = 0; kt < 32; ++kt) {
    __syncthreads();
    if (kt + 1 < 32) stage((kt + 1) & 1, kt + 1);
    const int buf = kt & 1;
    s16x8 af[4], bf[4];
#pragma unroll
    for (int mi = 0; mi < 4; ++mi) {
      int row = wm * 64 + mi * 16 + l15;
      int kc = lhi ^ ((row >> 1) & 3);
      af[mi] = *(const s16x8*)&ldsA[buf][row * 32 + kc * 8];
    }
#pragma unroll
    for (int ni = 0; ni < 4; ++ni) {
      int row = wn * 64 + ni * 16 + l15;
      int kc = lhi ^ ((row >> 1) & 3);
      bf[ni] = *(const s16x8*)&ldsB[buf][row * 32 + kc * 8];
    }
#pragma unroll
    for (int mi = 0; mi < 4; ++mi)
#pragma unroll
      for (int ni = 0; ni < 4; ++ni)
        acc[mi][ni] = MFMA16(af[mi], bf[ni], acc[mi][ni]);
  }

  // C layout: col = lane&15, row = (lane>>4)*4 + i
  if constexpr (MODE == 0) {
    float* dst = (float*)dstQ;
#pragma unroll
    for (int mi = 0; mi < 4; ++mi)
#pragma unroll
      for (int ni = 0; ni < 4; ++ni)
#pragma unroll
        for (int i = 0; i < 4; ++i) {
          int r = m0 + wm * 64 + mi * 16 + lhi * 4 + i;
          int n = n0 + wn * 64 + ni * 16 + l15;
          dst[(size_t)r * 1024 + n] = acc[mi][ni][i];
        }
  } else {  // MODE 3: fused QKV epilogue
    const int which = n0 >> 10;                 // 0=Q 1=K 2=V (uniform per block)
    if (which < 2) {
      unsigned short* dst = (unsigned short*)(which == 0 ? dstQ : dstK);
      const float sc = (which == 0) ? scale : 1.0f;
#pragma unroll
      for (int mi = 0; mi < 4; ++mi)
#pragma unroll
        for (int ni = 0; ni < 4; ++ni)
#pragma unroll
          for (int i = 0; i < 4; ++i) {
            int r = m0 + wm * 64 + mi * 16 + lhi * 4 + i;
            int nn = (n0 & 1023) + wn * 64 + ni * 16 + l15;
            float v = acc[mi][ni][i];
            float p = __shfl_xor(v, 1);         // RoPE partner
            int s = r & (SLEN - 1);
            int d = nn & 63;
            int fi = d >> 1;
            float c = ctab[s * 32 + fi], sn = stab[s * 32 + fi];
            float o = (d & 1) ? (p * sn + v * c) : (v * c - p * sn);
            o *= sc;
            int b = r >> 11, h = nn >> 6;
            dst[((size_t)(b * NHEADS + h) * SLEN + s) * 64 + d] = f2bf(o);
          }
    } else {  // V^T [bh][d][s]
      unsigned short* dst = (unsigned short*)dstV;
#pragma unroll
      for (int mi = 0; mi < 4; ++mi)
#pragma unroll
        for (int ni = 0; ni < 4; ++ni) {
          int r0 = m0 + wm * 64 + mi * 16 + lhi * 4;
          int nn = (n0 & 1023) + wn * 64 + ni * 16 + l15;
          int b = r0 >> 11, s0 = r0 & (SLEN - 1);
          int h = nn >> 6, d = nn & 63;
          s16x4 pk;
#pragma unroll
          for (int i = 0; i < 4; ++i) pk[i] = (short)f2bf(acc[mi][ni][i]);
          *(s16x4*)&dst[((size_t)(b * NHEADS + h) * 64 + d) * SLEN + s0] = pk;
        }
    }
  }
}

// ---------------- causal flash attention, v8: 32x32 swapped-QK ----------------
// Q,K: [bh][s][64] bf16 (Q pre-scaled by 0.125*log2e), Vt: [bh][64][s] bf16.
// 1024 blocks x 256 threads (4 waves), UNPAIRED, strict LPT dispatch order
// (t=15 blocks first). 4 blocks/CU (128KB LDS) -> 4 independent waves/SIMD.
// Full-rank swizzle SWZ(r) = (r&7)^((r>>3)&7): conflict-free b128 reads.
__global__ void __launch_bounds__(256, 4) flash_attn(const unsigned short* __restrict__ Q,
                                                     const unsigned short* __restrict__ K,
                                                     const unsigned short* __restrict__ Vt,
                                                     unsigned short* __restrict__ Obf) {
  __shared__ unsigned short Kbuf[2][64 * 64];   // 8 KB each
  __shared__ unsigned short Vbuf[2][64 * 64];   // rows = d, cols = k-local

  const int tid = threadIdx.x, lane = tid & 63, w = tid >> 6;
  const int l31 = lane & 31, h = lane >> 5;     // h: which 32-lane half

  // XCD chunking by bh + LPT (t descending in dispatch order)
  int id = blockIdx.x;                          // 0..1023
  int xcd = id & 7, idx = id >> 3;              // idx 0..127
  const int bh = xcd * 8 + (idx & 7);           // XCD k owns bh [8k, 8k+8)
  const int t = 15 - (idx >> 3);                // big q-tiles dispatched first
  const int b = bh >> 4, hd = bh & 15;

  const unsigned short* Qb = Q + (size_t)bh * SLEN * 64;
  const unsigned short* Kb = K + (size_t)bh * SLEN * 64;
  const unsigned short* Vb = Vt + (size_t)bh * 64 * SLEN;

  const int qbase = t * 128;
  const int nt = 2 * t + 2;                     // k-tiles incl. diagonal
  const int q_abs = qbase + w * 32 + l31;       // this lane's q column
  const int qminw = qbase + w * 32;             // wave's smallest q

  // stage one 64x64 K tile + one 64x64 Vt tile (16 instrs = 4/wave)
  auto stageKV = [&](int buf, int k0) {
#pragma unroll
    for (int i = 0; i < 2; ++i) {
      int c = i * 256 + tid;                    // 16B chunk 0..511
      int row = c >> 3, cg = c & 7;
      int col = ((cg ^ SWZ(row)) * 8);
      gload_lds16(Kb + (size_t)(k0 + row) * 64 + col, &Kbuf[buf][c * 8]);
      gload_lds16(Vb + (size_t)row * SLEN + k0 + col, &Vbuf[buf][c * 8]);
    }
  };

  // Q B-fragments: lane holds Q[q_abs][dc*16 + h*8 + j]
  s16x8 qf[4];
#pragma unroll
  for (int dc = 0; dc < 4; ++dc)
    qf[dc] = *(const s16x8*)&Qb[(size_t)q_abs * 64 + dc * 16 + h * 8];

  f32x16 accT[2] = {};                          // O^T: d = db*32+(r&3)+8*(r>>2)+4h
  float m_run = -3.0e38f, l_run = 0.f;

  stageKV(0, 0);
  for (int kt = 0; kt < nt; ++kt) {
    const int cur = kt & 1;
    const int k0 = kt * 64;
    if (kt + 1 < nt) {
      stageKV(cur ^ 1, (kt + 1) * 64);
      asm volatile("s_waitcnt vmcnt(4)" ::: "memory");   // stage(kt) landed; (kt+1) in flight
    } else {
      asm volatile("s_waitcnt vmcnt(0)" ::: "memory");
    }
    __builtin_amdgcn_s_barrier();
    __builtin_amdgcn_sched_barrier(0);

    {
      // S^T = K * Q^T : two 32-k blocks
      f32x16 sacc[2] = {};
#pragma unroll
      for (int kb = 0; kb < 2; ++kb) {
#pragma unroll
        for (int dc = 0; dc < 4; ++dc) {
          int r = kb * 32 + l31;
          int g = dc * 2 + h;
          s16x8 kf = *(const s16x8*)&Kbuf[cur][r * 64 + ((g ^ SWZ(r)) * 8)];
          sacc[kb] = MFMA32(kf, qf[dc], sacc[kb]);
        }
      }

      // causal mask on tiles overlapping the wave's q range
      // (k row of element r = (r&3)+8*(r>>2)+4h)
      if (k0 + 63 > qminw) {
#pragma unroll
        for (int kb = 0; kb < 2; ++kb)
#pragma unroll
          for (int r = 0; r < 16; ++r) {
            int k_abs = k0 + kb * 32 + (r & 3) + 8 * (r >> 2) + 4 * h;
            if (k_abs > q_abs) sacc[kb][r] = -3.0e38f;
          }
      }

      // lane-local max over 32 k + one cross-half combine
      float mx = sacc[0][0];
#pragma unroll
      for (int kb = 0; kb < 2; ++kb)
#pragma unroll
        for (int r = 0; r < 16; ++r) mx = fmaxf(mx, sacc[kb][r]);
      mx = fmaxf(mx, __shfl_xor(mx, 32));

      if (!__all(mx <= m_run)) {                // defer-rescale
        float mnew = fmaxf(m_run, mx);
        float facv = exp2f(m_run - mnew);
        m_run = mnew;
        l_run *= facv;
#pragma unroll
        for (int db = 0; db < 2; ++db)
#pragma unroll
          for (int r = 0; r < 16; ++r) accT[db][r] *= facv;
      }

      // exp2 + lane-local sum + cross-half combine
      float sum = 0.f;
#pragma unroll
      for (int kb = 0; kb < 2; ++kb)
#pragma unroll
        for (int r = 0; r < 16; ++r) {
          float p = exp2f(sacc[kb][r] - m_run);
          sacc[kb][r] = p;
          sum += p;
        }
      l_run += sum + __shfl_xor(sum, 32);

      // pack P to bf16 PV B-frags in-register.
      // Holder u32s: H[u][i], u = kb*4+q4 covers k = kb*32+8*q4+4h + {0..3}.
      unsigned Hv[8][2];
#pragma unroll
      for (int kb = 0; kb < 2; ++kb)
#pragma unroll
        for (int q4 = 0; q4 < 4; ++q4) {
          Hv[kb * 4 + q4][0] = cvt_pk_bf16(sacc[kb][q4 * 4 + 0], sacc[kb][q4 * 4 + 1]);
          Hv[kb * 4 + q4][1] = cvt_pk_bf16(sacc[kb][q4 * 4 + 2], sacc[kb][q4 * 4 + 3]);
        }
      // Frag c needs k = c*16 + 8h + j (j=0..7): j0..3 from h'=0 holder,
      // j4..7 from h'=1 holder, both at u = 2c + h (this lane's h).
      s16x8 pf[4];
#pragma unroll
      for (int c = 0; c < 4; ++c) {
        unsigned loc0 = h ? Hv[2 * c + 1][0] : Hv[2 * c][0];
        unsigned loc1 = h ? Hv[2 * c + 1][1] : Hv[2 * c][1];
        unsigned snd0 = h ? Hv[2 * c][0] : Hv[2 * c + 1][0];
        unsigned snd1 = h ? Hv[2 * c][1] : Hv[2 * c + 1][1];
        unsigned rcv0 = (unsigned)__shfl_xor((int)snd0, 32);
        unsigned rcv1 = (unsigned)__shfl_xor((int)snd1, 32);
        u32x4 tv;
        tv[0] = h ? rcv0 : loc0;                // k j0..3  (h'=0 holder)
        tv[1] = h ? rcv1 : loc1;
        tv[2] = h ? loc0 : rcv0;                // k j4..7  (h'=1 holder)
        tv[3] = h ? loc1 : rcv1;
        pf[c] = __builtin_bit_cast(s16x8, tv);
      }

      // PV: O^T += Vt (A, LDS) * P (B, regs)
#pragma unroll
      for (int db = 0; db < 2; ++db)
#pragma unroll
        for (int kc = 0; kc < 4; ++kc) {
          int r = db * 32 + l31;
          int g = kc * 2 + h;
          s16x8 vf = *(const s16x8*)&Vbuf[cur][r * 64 + ((g ^ SWZ(r)) * 8)];
          accT[db] = MFMA32(vf, pf[kc], accT[db]);
        }
    }

    __builtin_amdgcn_sched_barrier(0);
    __builtin_amdgcn_s_barrier();
  }

  // normalize (lane-local) and store O^T -> [b][s][h*64+d]
  float linv = 1.f / l_run;
#pragma unroll
  for (int db = 0; db < 2; ++db)
#pragma unroll
    for (int q4 = 0; q4 < 4; ++q4) {
      u32x2 pk;
      pk[0] = cvt_pk_bf16(accT[db][q4 * 4 + 0] * linv, accT[db][q4 * 4 + 1] * linv);
      pk[1] = cvt_pk_bf16(accT[db][q4 * 4 + 2] * linv, accT[db][q4 * 4 + 3] * linv);
      int d0 = db * 32 + 8 * q4 + 4 * h;
      *(u32x2*)&Obf[((size_t)(b * SLEN + q_abs)) * DMODEL + hd * 64 + d0] = pk;
    }
}

extern "C" void kernel_launch(void* const* d_in, const int* in_sizes, int n_in,
                              void* d_out, int out_size, void* d_ws, size_t ws_size,
                              hipStream_t stream) {
  const float* x  = (const float*)d_in[0];
  const float* Wq = (const float*)d_in[1];
  const float* Wk = (const float*)d_in[2];
  const float* Wv = (const float*)d_in[3];
  const float* Wo = (const float*)d_in[4];
  const int* pos  = (const int*)d_in[5];
  float* out = (float*)d_out;

  char* ws = (char*)d_ws;
  size_t off = 0;
  auto take = [&](size_t bytes) {
    char* p = ws + off;
    off += (bytes + 255) & ~(size_t)255;
    return p;
  };
  unsigned short* xbf  = (unsigned short*)take((size_t)MTOT * DMODEL * 2);
  unsigned short* wqkv = (unsigned short*)take((size_t)3 * DMODEL * DMODEL * 2);
  unsigned short* wobf = (unsigned short*)take((size_t)DMODEL * DMODEL * 2);
  unsigned short* Qs   = (unsigned short*)take((size_t)64 * SLEN * 64 * 2);
  unsigned short* Ks   = (unsigned short*)take((size_t)64 * SLEN * 64 * 2);
  unsigned short* Vt   = (unsigned short*)take((size_t)64 * 64 * SLEN * 2);
  unsigned short* Obf  = (unsigned short*)take((size_t)MTOT * DMODEL * 2);
  float* ctab = (float*)take((size_t)SLEN * 32 * 4);
  float* stab = (float*)take((size_t)SLEN * 32 * 4);

  rope_table<<<256, 256, 0, stream>>>(pos, ctab, stab);
  cvt_f32_bf16<<<4096, 256, 0, stream>>>(x, xbf, MTOT * DMODEL / 8);
  // Wq, Wk, Wv land contiguously as W_qkv[3072][1024]; Wo separate.
  cvt_weights<<<dim3(512, 4), 256, 0, stream>>>(
      Wq, Wk, Wv, Wo,
      wqkv, wqkv + (size_t)DMODEL * DMODEL, wqkv + (size_t)2 * DMODEL * DMODEL, wobf);

  // fused QKV projection: C[8192][3072], epilogue routes per 128-col block
  gemm_nt<3><<<dim3(24, 64), 256, 0, stream>>>(xbf, wqkv, Qs, Ks, Vt,
                                               ctab, stab, 0.18033688011112042f);

  flash_attn<<<1024, 256, 0, stream>>>(Qs, Ks, Vt, Obf);

  // final projection, fp32 output
  gemm_nt<0><<<dim3(8, 64), 256, 0, stream>>>(Obf, wobf, out, nullptr, nullptr,
                                              nullptr, nullptr, 1.0f);
}

// Round 10
// 188.828 us; speedup vs baseline: 1.3344x; 1.0635x over previous
//
#include <hip/hip_runtime.h>
#include <stdint.h>

#define SLEN 2048
#define DMODEL 1024
#define NHEADS 16
#define MTOT 8192   // 4 * 2048

typedef short s16x8 __attribute__((ext_vector_type(8)));
typedef short s16x4 __attribute__((ext_vector_type(4)));
typedef float f32x4 __attribute__((ext_vector_type(4)));
typedef float f32x16 __attribute__((ext_vector_type(16)));
typedef unsigned u32x2 __attribute__((ext_vector_type(2)));
typedef unsigned u32x4 __attribute__((ext_vector_type(4)));

static __device__ __forceinline__ unsigned short f2bf(float f) {
  unsigned u = __builtin_bit_cast(unsigned, f);
  u += 0x7fffu + ((u >> 16) & 1u);           // RNE
  return (unsigned short)(u >> 16);
}

static __device__ __forceinline__ unsigned cvt_pk_bf16(float lo, float hi) {
  unsigned r;
  asm("v_cvt_pk_bf16_f32 %0, %1, %2" : "=v"(r) : "v"(lo), "v"(hi));
  return r;
}

static __device__ __forceinline__ void gload_lds16(const void* g, void* l) {
  __builtin_amdgcn_global_load_lds((__attribute__((address_space(1))) void*)g,
                                   (__attribute__((address_space(3))) void*)l,
                                   16, 0, 0);
}

#define MFMA16(a, b, c) __builtin_amdgcn_mfma_f32_16x16x32_bf16(a, b, c, 0, 0, 0)
#define MFMA32(a, b, c) __builtin_amdgcn_mfma_f32_32x32x16_bf16(a, b, c, 0, 0, 0)
// full-rank row swizzle: rows r, r+8, r+16, ... get distinct granule perms
#define SWZ(r) ((((r) & 7) ^ (((r) >> 3) & 7)))

// ---------------- RoPE cos/sin table: [2048][32] each ----------------
__global__ void __launch_bounds__(256) rope_table(const int* __restrict__ pos,
                                                  float* __restrict__ ctab,
                                                  float* __restrict__ stab) {
  int g = blockIdx.x * 256 + threadIdx.x;     // 65536 total
  int s = g >> 5, i = g & 31;
  float p = (float)pos[s];
  float ang = p * exp2f(-(float)i * 0.41524101186092029f);
  ctab[g] = cosf(ang);
  stab[g] = sinf(ang);
}

// ---------------- fp32 -> bf16 convert (x8 vectorized) ----------------
__global__ void __launch_bounds__(256) cvt_f32_bf16(const float* __restrict__ src,
                                                    unsigned short* __restrict__ dst,
                                                    int n8) {
  int i = blockIdx.x * 256 + threadIdx.x;
  if (i >= n8) return;
  f32x4 a = ((const f32x4*)src)[i * 2];
  f32x4 b = ((const f32x4*)src)[i * 2 + 1];
  s16x8 o;
#pragma unroll
  for (int j = 0; j < 4; ++j) o[j] = (short)f2bf(a[j]);
#pragma unroll
  for (int j = 0; j < 4; ++j) o[4 + j] = (short)f2bf(b[j]);
  ((s16x8*)dst)[i] = o;
}

// all four weight matrices in one dispatch (grid.y selects)
__global__ void __launch_bounds__(256) cvt_weights(const float* __restrict__ w0,
                                                   const float* __restrict__ w1,
                                                   const float* __restrict__ w2,
                                                   const float* __restrict__ w3,
                                                   unsigned short* __restrict__ d0,
                                                   unsigned short* __restrict__ d1,
                                                   unsigned short* __restrict__ d2,
                                                   unsigned short* __restrict__ d3) {
  int which = blockIdx.y;
  const float* src = which == 0 ? w0 : which == 1 ? w1 : which == 2 ? w2 : w3;
  unsigned short* dst = which == 0 ? d0 : which == 1 ? d1 : which == 2 ? d2 : d3;
  int i = blockIdx.x * 256 + threadIdx.x;     // 131072 per matrix
  f32x4 a = ((const f32x4*)src)[i * 2];
  f32x4 b = ((const f32x4*)src)[i * 2 + 1];
  s16x8 o;
#pragma unroll
  for (int j = 0; j < 4; ++j) o[j] = (short)f2bf(a[j]);
#pragma unroll
  for (int j = 0; j < 4; ++j) o[4 + j] = (short)f2bf(b[j]);
  ((s16x8*)dst)[i] = o;
}

// ---------------- GEMM: C[M=8192][N] = A[M][K=1024] * B[N][K]^T --------------
// MODE 0: N=1024, store f32 row-major (final Wo projection)
// MODE 3: N=3072 fused QKV against concatenated W_qkv. Per 128-col block:
//         n0>>10 == 0 -> Q (RoPE + scale), 1 -> K (RoPE), 2 -> V^T store.
// XCD mapping: per-XCD working set <= A 2MB + B 2MB = 4MB L2 (n in groups of 8).
// Main loop: 3-buffer 2-deep prefetch with COUNTED vmcnt (never 0 mid-loop)
// + raw s_barrier — each stage gets ~2 k-steps to land; no per-step drain.
// Race-safety: barrier at step kt guarantees all waves consumed buf[(kt+2)%3]
// during step kt-1 before stage(kt+2) overwrites it.
template<int MODE>
__global__ void __launch_bounds__(256) gemm_nt(const unsigned short* __restrict__ A,
                                               const unsigned short* __restrict__ B,
                                               void* __restrict__ dstQ,
                                               void* __restrict__ dstK,
                                               void* __restrict__ dstV,
                                               const float* __restrict__ ctab,
                                               const float* __restrict__ stab,
                                               float scale) {
  __shared__ unsigned short ldsA[3][128 * 32];
  __shared__ unsigned short ldsB[3][128 * 32];
  const int tid = threadIdx.x;
  const int lane = tid & 63;
  const int wave = tid >> 6;
  const int wm = wave >> 1, wn = wave & 1;

  int m0, n0;
  if constexpr (MODE == 3) {
    int flat = blockIdx.y * 24 + blockIdx.x;    // 1536 blocks
    int xcd = flat & 7, idx = flat >> 3;        // idx 0..191 (per-XCD issue order)
    int g = idx >> 6;                           // n-group 0..2 (8 n-blocks each)
    int local = idx & 63;
    int lm = local >> 3, ln = local & 7;
    m0 = (xcd * 8 + lm) * 128;
    n0 = (g * 8 + ln) * 128;
  } else {
    int flat = blockIdx.y * 8 + blockIdx.x;     // 512 blocks
    int logical = (flat & 7) * 64 + (flat >> 3);
    m0 = (logical >> 3) * 128;
    n0 = (logical & 7) * 128;
  }
  const int l15 = lane & 15, lhi = lane >> 4;

  f32x4 acc[4][4] = {};

  auto stage = [&](int buf, int kt) {
    const int kbase = kt * 32;
#pragma unroll
    for (int issue = 0; issue < 2; ++issue) {
      int c = issue * 256 + wave * 64 + lane;   // chunk id 0..511
      int row = c >> 2, kc = c & 3;
      int kcg = kc ^ ((row >> 1) & 3);          // source chunk for this slot
      gload_lds16(A + (size_t)(m0 + row) * 1024 + kbase + kcg * 8,
                  &ldsA[buf][(issue * 256 + wave * 64) * 8]);
      gload_lds16(B + (size_t)(n0 + row) * 1024 + kbase + kcg * 8,
                  &ldsB[buf][(issue * 256 + wave * 64) * 8]);
    }
  };

  // 2-deep prologue: 8 loads/wave in flight
  stage(0, 0);
  stage(1, 1);
  for (int kt = 0; kt < 32; ++kt) {
    // wait for stage(kt)'s 4 loads; keep stage(kt+1)'s 4 in flight
    if (kt + 1 < 32) {
      asm volatile("s_waitcnt vmcnt(4)" ::: "memory");
    } else {
      asm volatile("s_waitcnt vmcnt(0)" ::: "memory");
    }
    __builtin_amdgcn_s_barrier();
    __builtin_amdgcn_sched_barrier(0);
    if (kt + 2 < 32) stage((kt + 2) % 3, kt + 2);

    const int buf = kt % 3;
    s16x8 af[4], bf[4];
#pragma unroll
    for (int mi = 0; mi < 4; ++mi) {
      int row = wm * 64 + mi * 16 + l15;
      int kc = lhi ^ ((row >> 1) & 3);
      af[mi] = *(const s16x8*)&ldsA[buf][row * 32 + kc * 8];
    }
#pragma unroll
    for (int ni = 0; ni < 4; ++ni) {
      int row = wn * 64 + ni * 16 + l15;
      int kc = lhi ^ ((row >> 1) & 3);
      bf[ni] = *(const s16x8*)&ldsB[buf][row * 32 + kc * 8];
    }
#pragma unroll
    for (int mi = 0; mi < 4; ++mi)
#pragma unroll
      for (int ni = 0; ni < 4; ++ni)
        acc[mi][ni] = MFMA16(af[mi], bf[ni], acc[mi][ni]);
  }

  // C layout: col = lane&15, row = (lane>>4)*4 + i
  if constexpr (MODE == 0) {
    float* dst = (float*)dstQ;
#pragma unroll
    for (int mi = 0; mi < 4; ++mi)
#pragma unroll
      for (int ni = 0; ni < 4; ++ni)
#pragma unroll
        for (int i = 0; i < 4; ++i) {
          int r = m0 + wm * 64 + mi * 16 + lhi * 4 + i;
          int n = n0 + wn * 64 + ni * 16 + l15;
          dst[(size_t)r * 1024 + n] = acc[mi][ni][i];
        }
  } else {  // MODE 3: fused QKV epilogue
    const int which = n0 >> 10;                 // 0=Q 1=K 2=V (uniform per block)
    if (which < 2) {
      unsigned short* dst = (unsigned short*)(which == 0 ? dstQ : dstK);
      const float sc = (which == 0) ? scale : 1.0f;
#pragma unroll
      for (int mi = 0; mi < 4; ++mi)
#pragma unroll
        for (int ni = 0; ni < 4; ++ni)
#pragma unroll
          for (int i = 0; i < 4; ++i) {
            int r = m0 + wm * 64 + mi * 16 + lhi * 4 + i;
            int nn = (n0 & 1023) + wn * 64 + ni * 16 + l15;
            float v = acc[mi][ni][i];
            float p = __shfl_xor(v, 1);         // RoPE partner
            int s = r & (SLEN - 1);
            int d = nn & 63;
            int fi = d >> 1;
            float c = ctab[s * 32 + fi], sn = stab[s * 32 + fi];
            float o = (d & 1) ? (p * sn + v * c) : (v * c - p * sn);
            o *= sc;
            int b = r >> 11, h = nn >> 6;
            dst[((size_t)(b * NHEADS + h) * SLEN + s) * 64 + d] = f2bf(o);
          }
    } else {  // V^T [bh][d][s]
      unsigned short* dst = (unsigned short*)dstV;
#pragma unroll
      for (int mi = 0; mi < 4; ++mi)
#pragma unroll
        for (int ni = 0; ni < 4; ++ni) {
          int r0 = m0 + wm * 64 + mi * 16 + lhi * 4;
          int nn = (n0 & 1023) + wn * 64 + ni * 16 + l15;
          int b = r0 >> 11, s0 = r0 & (SLEN - 1);
          int h = nn >> 6, d = nn & 63;
          s16x4 pk;
#pragma unroll
          for (int i = 0; i < 4; ++i) pk[i] = (short)f2bf(acc[mi][ni][i]);
          *(s16x4*)&dst[((size_t)(b * NHEADS + h) * 64 + d) * SLEN + s0] = pk;
        }
    }
  }
}

// ---------------- causal flash attention, v8: 32x32 swapped-QK ----------------
// Q,K: [bh][s][64] bf16 (Q pre-scaled by 0.125*log2e), Vt: [bh][64][s] bf16.
// 1024 blocks x 256 threads (4 waves), UNPAIRED, strict LPT dispatch order
// (t=15 blocks first). 4 blocks/CU (128KB LDS) -> 4 independent waves/SIMD.
// Full-rank swizzle SWZ(r) = (r&7)^((r>>3)&7): conflict-free b128 reads.
__global__ void __launch_bounds__(256, 4) flash_attn(const unsigned short* __restrict__ Q,
                                                     const unsigned short* __restrict__ K,
                                                     const unsigned short* __restrict__ Vt,
                                                     unsigned short* __restrict__ Obf) {
  __shared__ unsigned short Kbuf[2][64 * 64];   // 8 KB each
  __shared__ unsigned short Vbuf[2][64 * 64];   // rows = d, cols = k-local

  const int tid = threadIdx.x, lane = tid & 63, w = tid >> 6;
  const int l31 = lane & 31, h = lane >> 5;     // h: which 32-lane half

  // XCD chunking by bh + LPT (t descending in dispatch order)
  int id = blockIdx.x;                          // 0..1023
  int xcd = id & 7, idx = id >> 3;              // idx 0..127
  const int bh = xcd * 8 + (idx & 7);           // XCD k owns bh [8k, 8k+8)
  const int t = 15 - (idx >> 3);                // big q-tiles dispatched first
  const int b = bh >> 4, hd = bh & 15;

  const unsigned short* Qb = Q + (size_t)bh * SLEN * 64;
  const unsigned short* Kb = K + (size_t)bh * SLEN * 64;
  const unsigned short* Vb = Vt + (size_t)bh * 64 * SLEN;

  const int qbase = t * 128;
  const int nt = 2 * t + 2;                     // k-tiles incl. diagonal
  const int q_abs = qbase + w * 32 + l31;       // this lane's q column
  const int qminw = qbase + w * 32;             // wave's smallest q

  // stage one 64x64 K tile + one 64x64 Vt tile (16 instrs = 4/wave)
  auto stageKV = [&](int buf, int k0) {
#pragma unroll
    for (int i = 0; i < 2; ++i) {
      int c = i * 256 + tid;                    // 16B chunk 0..511
      int row = c >> 3, cg = c & 7;
      int col = ((cg ^ SWZ(row)) * 8);
      gload_lds16(Kb + (size_t)(k0 + row) * 64 + col, &Kbuf[buf][c * 8]);
      gload_lds16(Vb + (size_t)row * SLEN + k0 + col, &Vbuf[buf][c * 8]);
    }
  };

  // Q B-fragments: lane holds Q[q_abs][dc*16 + h*8 + j]
  s16x8 qf[4];
#pragma unroll
  for (int dc = 0; dc < 4; ++dc)
    qf[dc] = *(const s16x8*)&Qb[(size_t)q_abs * 64 + dc * 16 + h * 8];

  f32x16 accT[2] = {};                          // O^T: d = db*32+(r&3)+8*(r>>2)+4h
  float m_run = -3.0e38f, l_run = 0.f;

  stageKV(0, 0);
  for (int kt = 0; kt < nt; ++kt) {
    const int cur = kt & 1;
    const int k0 = kt * 64;
    if (kt + 1 < nt) {
      stageKV(cur ^ 1, (kt + 1) * 64);
      asm volatile("s_waitcnt vmcnt(4)" ::: "memory");   // stage(kt) landed; (kt+1) in flight
    } else {
      asm volatile("s_waitcnt vmcnt(0)" ::: "memory");
    }
    __builtin_amdgcn_s_barrier();
    __builtin_amdgcn_sched_barrier(0);

    {
      // S^T = K * Q^T : two 32-k blocks
      f32x16 sacc[2] = {};
#pragma unroll
      for (int kb = 0; kb < 2; ++kb) {
#pragma unroll
        for (int dc = 0; dc < 4; ++dc) {
          int r = kb * 32 + l31;
          int g = dc * 2 + h;
          s16x8 kf = *(const s16x8*)&Kbuf[cur][r * 64 + ((g ^ SWZ(r)) * 8)];
          sacc[kb] = MFMA32(kf, qf[dc], sacc[kb]);
        }
      }

      // causal mask on tiles overlapping the wave's q range
      // (k row of element r = (r&3)+8*(r>>2)+4h)
      if (k0 + 63 > qminw) {
#pragma unroll
        for (int kb = 0; kb < 2; ++kb)
#pragma unroll
          for (int r = 0; r < 16; ++r) {
            int k_abs = k0 + kb * 32 + (r & 3) + 8 * (r >> 2) + 4 * h;
            if (k_abs > q_abs) sacc[kb][r] = -3.0e38f;
          }
      }

      // lane-local max over 32 k + one cross-half combine
      float mx = sacc[0][0];
#pragma unroll
      for (int kb = 0; kb < 2; ++kb)
#pragma unroll
        for (int r = 0; r < 16; ++r) mx = fmaxf(mx, sacc[kb][r]);
      mx = fmaxf(mx, __shfl_xor(mx, 32));

      if (!__all(mx <= m_run)) {                // defer-rescale
        float mnew = fmaxf(m_run, mx);
        float facv = exp2f(m_run - mnew);
        m_run = mnew;
        l_run *= facv;
#pragma unroll
        for (int db = 0; db < 2; ++db)
#pragma unroll
          for (int r = 0; r < 16; ++r) accT[db][r] *= facv;
      }

      // exp2 + lane-local sum + cross-half combine
      float sum = 0.f;
#pragma unroll
      for (int kb = 0; kb < 2; ++kb)
#pragma unroll
        for (int r = 0; r < 16; ++r) {
          float p = exp2f(sacc[kb][r] - m_run);
          sacc[kb][r] = p;
          sum += p;
        }
      l_run += sum + __shfl_xor(sum, 32);

      // pack P to bf16 PV B-frags in-register.
      // Holder u32s: H[u][i], u = kb*4+q4 covers k = kb*32+8*q4+4h + {0..3}.
      unsigned Hv[8][2];
#pragma unroll
      for (int kb = 0; kb < 2; ++kb)
#pragma unroll
        for (int q4 = 0; q4 < 4; ++q4) {
          Hv[kb * 4 + q4][0] = cvt_pk_bf16(sacc[kb][q4 * 4 + 0], sacc[kb][q4 * 4 + 1]);
          Hv[kb * 4 + q4][1] = cvt_pk_bf16(sacc[kb][q4 * 4 + 2], sacc[kb][q4 * 4 + 3]);
        }
      // Frag c needs k = c*16 + 8h + j (j=0..7): j0..3 from h'=0 holder,
      // j4..7 from h'=1 holder, both at u = 2c + h (this lane's h).
      s16x8 pf[4];
#pragma unroll
      for (int c = 0; c < 4; ++c) {
        unsigned loc0 = h ? Hv[2 * c + 1][0] : Hv[2 * c][0];
        unsigned loc1 = h ? Hv[2 * c + 1][1] : Hv[2 * c][1];
        unsigned snd0 = h ? Hv[2 * c][0] : Hv[2 * c + 1][0];
        unsigned snd1 = h ? Hv[2 * c][1] : Hv[2 * c + 1][1];
        unsigned rcv0 = (unsigned)__shfl_xor((int)snd0, 32);
        unsigned rcv1 = (unsigned)__shfl_xor((int)snd1, 32);
        u32x4 tv;
        tv[0] = h ? rcv0 : loc0;                // k j0..3  (h'=0 holder)
        tv[1] = h ? rcv1 : loc1;
        tv[2] = h ? loc0 : rcv0;                // k j4..7  (h'=1 holder)
        tv[3] = h ? loc1 : rcv1;
        pf[c] = __builtin_bit_cast(s16x8, tv);
      }

      // PV: O^T += Vt (A, LDS) * P (B, regs)
#pragma unroll
      for (int db = 0; db < 2; ++db)
#pragma unroll
        for (int kc = 0; kc < 4; ++kc) {
          int r = db * 32 + l31;
          int g = kc * 2 + h;
          s16x8 vf = *(const s16x8*)&Vbuf[cur][r * 64 + ((g ^ SWZ(r)) * 8)];
          accT[db] = MFMA32(vf, pf[kc], accT[db]);
        }
    }

    __builtin_amdgcn_sched_barrier(0);
    __builtin_amdgcn_s_barrier();
  }

  // normalize (lane-local) and store O^T -> [b][s][h*64+d]
  float linv = 1.f / l_run;
#pragma unroll
  for (int db = 0; db < 2; ++db)
#pragma unroll
    for (int q4 = 0; q4 < 4; ++q4) {
      u32x2 pk;
      pk[0] = cvt_pk_bf16(accT[db][q4 * 4 + 0] * linv, accT[db][q4 * 4 + 1] * linv);
      pk[1] = cvt_pk_bf16(accT[db][q4 * 4 + 2] * linv, accT[db][q4 * 4 + 3] * linv);
      int d0 = db * 32 + 8 * q4 + 4 * h;
      *(u32x2*)&Obf[((size_t)(b * SLEN + q_abs)) * DMODEL + hd * 64 + d0] = pk;
    }
}

extern "C" void kernel_launch(void* const* d_in, const int* in_sizes, int n_in,
                              void* d_out, int out_size, void* d_ws, size_t ws_size,
                              hipStream_t stream) {
  const float* x  = (const float*)d_in[0];
  const float* Wq = (const float*)d_in[1];
  const float* Wk = (const float*)d_in[2];
  const float* Wv = (const float*)d_in[3];
  const float* Wo = (const float*)d_in[4];
  const int* pos  = (const int*)d_in[5];
  float* out = (float*)d_out;

  char* ws = (char*)d_ws;
  size_t off = 0;
  auto take = [&](size_t bytes) {
    char* p = ws + off;
    off += (bytes + 255) & ~(size_t)255;
    return p;
  };
  unsigned short* xbf  = (unsigned short*)take((size_t)MTOT * DMODEL * 2);
  unsigned short* wqkv = (unsigned short*)take((size_t)3 * DMODEL * DMODEL * 2);
  unsigned short* wobf = (unsigned short*)take((size_t)DMODEL * DMODEL * 2);
  unsigned short* Qs   = (unsigned short*)take((size_t)64 * SLEN * 64 * 2);
  unsigned short* Ks   = (unsigned short*)take((size_t)64 * SLEN * 64 * 2);
  unsigned short* Vt   = (unsigned short*)take((size_t)64 * 64 * SLEN * 2);
  unsigned short* Obf  = (unsigned short*)take((size_t)MTOT * DMODEL * 2);
  float* ctab = (float*)take((size_t)SLEN * 32 * 4);
  float* stab = (float*)take((size_t)SLEN * 32 * 4);

  rope_table<<<256, 256, 0, stream>>>(pos, ctab, stab);
  cvt_f32_bf16<<<4096, 256, 0, stream>>>(x, xbf, MTOT * DMODEL / 8);
  // Wq, Wk, Wv land contiguously as W_qkv[3072][1024]; Wo separate.
  cvt_weights<<<dim3(512, 4), 256, 0, stream>>>(
      Wq, Wk, Wv, Wo,
      wqkv, wqkv + (size_t)DMODEL * DMODEL, wqkv + (size_t)2 * DMODEL * DMODEL, wobf);

  // fused QKV projection: C[8192][3072], epilogue routes per 128-col block
  gemm_nt<3><<<dim3(24, 64), 256, 0, stream>>>(xbf, wqkv, Qs, Ks, Vt,
                                               ctab, stab, 0.18033688011112042f);

  flash_attn<<<1024, 256, 0, stream>>>(Qs, Ks, Vt, Obf);

  // final projection, fp32 output
  gemm_nt<0><<<dim3(8, 64), 256, 0, stream>>>(Obf, wobf, out, nullptr, nullptr,
                                              nullptr, nullptr, 1.0f);
}

// Round 11
// 188.560 us; speedup vs baseline: 1.3363x; 1.0014x over previous
//
#include <hip/hip_runtime.h>
#include <stdint.h>

#define SLEN 2048
#define DMODEL 1024
#define NHEADS 16
#define MTOT 8192   // 4 * 2048

typedef short s16x8 __attribute__((ext_vector_type(8)));
typedef short s16x4 __attribute__((ext_vector_type(4)));
typedef float f32x4 __attribute__((ext_vector_type(4)));
typedef float f32x16 __attribute__((ext_vector_type(16)));
typedef unsigned u32x2 __attribute__((ext_vector_type(2)));
typedef unsigned u32x4 __attribute__((ext_vector_type(4)));

static __device__ __forceinline__ unsigned short f2bf(float f) {
  unsigned u = __builtin_bit_cast(unsigned, f);
  u += 0x7fffu + ((u >> 16) & 1u);           // RNE
  return (unsigned short)(u >> 16);
}

static __device__ __forceinline__ unsigned cvt_pk_bf16(float lo, float hi) {
  unsigned r;
  asm("v_cvt_pk_bf16_f32 %0, %1, %2" : "=v"(r) : "v"(lo), "v"(hi));
  return r;
}

static __device__ __forceinline__ void gload_lds16(const void* g, void* l) {
  __builtin_amdgcn_global_load_lds((__attribute__((address_space(1))) void*)g,
                                   (__attribute__((address_space(3))) void*)l,
                                   16, 0, 0);
}

#define MFMA16(a, b, c) __builtin_amdgcn_mfma_f32_16x16x32_bf16(a, b, c, 0, 0, 0)
#define MFMA32(a, b, c) __builtin_amdgcn_mfma_f32_32x32x16_bf16(a, b, c, 0, 0, 0)
// full-rank row swizzle: rows r, r+8, r+16, ... get distinct granule perms
#define SWZ(r) ((((r) & 7) ^ (((r) >> 3) & 7)))

// ---------------- RoPE cos/sin table: [2048][32] each ----------------
__global__ void __launch_bounds__(256) rope_table(const int* __restrict__ pos,
                                                  float* __restrict__ ctab,
                                                  float* __restrict__ stab) {
  int g = blockIdx.x * 256 + threadIdx.x;     // 65536 total
  int s = g >> 5, i = g & 31;
  float p = (float)pos[s];
  float ang = p * exp2f(-(float)i * 0.41524101186092029f);
  ctab[g] = cosf(ang);
  stab[g] = sinf(ang);
}

// ---------------- fp32 -> bf16 convert (x8 vectorized) ----------------
__global__ void __launch_bounds__(256) cvt_f32_bf16(const float* __restrict__ src,
                                                    unsigned short* __restrict__ dst,
                                                    int n8) {
  int i = blockIdx.x * 256 + threadIdx.x;
  if (i >= n8) return;
  f32x4 a = ((const f32x4*)src)[i * 2];
  f32x4 b = ((const f32x4*)src)[i * 2 + 1];
  s16x8 o;
#pragma unroll
  for (int j = 0; j < 4; ++j) o[j] = (short)f2bf(a[j]);
#pragma unroll
  for (int j = 0; j < 4; ++j) o[4 + j] = (short)f2bf(b[j]);
  ((s16x8*)dst)[i] = o;
}

// all four weight matrices in one dispatch (grid.y selects)
__global__ void __launch_bounds__(256) cvt_weights(const float* __restrict__ w0,
                                                   const float* __restrict__ w1,
                                                   const float* __restrict__ w2,
                                                   const float* __restrict__ w3,
                                                   unsigned short* __restrict__ d0,
                                                   unsigned short* __restrict__ d1,
                                                   unsigned short* __restrict__ d2,
                                                   unsigned short* __restrict__ d3) {
  int which = blockIdx.y;
  const float* src = which == 0 ? w0 : which == 1 ? w1 : which == 2 ? w2 : w3;
  unsigned short* dst = which == 0 ? d0 : which == 1 ? d1 : which == 2 ? d2 : d3;
  int i = blockIdx.x * 256 + threadIdx.x;     // 131072 per matrix
  f32x4 a = ((const f32x4*)src)[i * 2];
  f32x4 b = ((const f32x4*)src)[i * 2 + 1];
  s16x8 o;
#pragma unroll
  for (int j = 0; j < 4; ++j) o[j] = (short)f2bf(a[j]);
#pragma unroll
  for (int j = 0; j < 4; ++j) o[4 + j] = (short)f2bf(b[j]);
  ((s16x8*)dst)[i] = o;
}

// ---------------- GEMM: C[M=8192][N] = A[M][K=1024] * B[N][K]^T --------------
// MODE 0: N=1024, store f32 row-major (final Wo projection)
// MODE 3: N=3072 fused QKV against concatenated W_qkv. Per 128-col block:
//         n0>>10 == 0 -> Q (RoPE + scale), 1 -> K (RoPE), 2 -> V^T store.
// XCD mapping: per-XCD working set <= A 2MB + B 2MB = 4MB L2 (n in groups of 8).
// Main loop: 3-buffer 2-deep prefetch with COUNTED vmcnt (never 0 mid-loop)
// + raw s_barrier — each stage gets ~2 k-steps to land; no per-step drain.
// (R10: cut QKV 94 -> ~60 us.)
template<int MODE>
__global__ void __launch_bounds__(256) gemm_nt(const unsigned short* __restrict__ A,
                                               const unsigned short* __restrict__ B,
                                               void* __restrict__ dstQ,
                                               void* __restrict__ dstK,
                                               void* __restrict__ dstV,
                                               const float* __restrict__ ctab,
                                               const float* __restrict__ stab,
                                               float scale) {
  __shared__ unsigned short ldsA[3][128 * 32];
  __shared__ unsigned short ldsB[3][128 * 32];
  const int tid = threadIdx.x;
  const int lane = tid & 63;
  const int wave = tid >> 6;
  const int wm = wave >> 1, wn = wave & 1;

  int m0, n0;
  if constexpr (MODE == 3) {
    int flat = blockIdx.y * 24 + blockIdx.x;    // 1536 blocks
    int xcd = flat & 7, idx = flat >> 3;        // idx 0..191 (per-XCD issue order)
    int g = idx >> 6;                           // n-group 0..2 (8 n-blocks each)
    int local = idx & 63;
    int lm = local >> 3, ln = local & 7;
    m0 = (xcd * 8 + lm) * 128;
    n0 = (g * 8 + ln) * 128;
  } else {
    int flat = blockIdx.y * 8 + blockIdx.x;     // 512 blocks
    int logical = (flat & 7) * 64 + (flat >> 3);
    m0 = (logical >> 3) * 128;
    n0 = (logical & 7) * 128;
  }
  const int l15 = lane & 15, lhi = lane >> 4;

  f32x4 acc[4][4] = {};

  auto stage = [&](int buf, int kt) {
    const int kbase = kt * 32;
#pragma unroll
    for (int issue = 0; issue < 2; ++issue) {
      int c = issue * 256 + wave * 64 + lane;   // chunk id 0..511
      int row = c >> 2, kc = c & 3;
      int kcg = kc ^ ((row >> 1) & 3);          // source chunk for this slot
      gload_lds16(A + (size_t)(m0 + row) * 1024 + kbase + kcg * 8,
                  &ldsA[buf][(issue * 256 + wave * 64) * 8]);
      gload_lds16(B + (size_t)(n0 + row) * 1024 + kbase + kcg * 8,
                  &ldsB[buf][(issue * 256 + wave * 64) * 8]);
    }
  };

  // 2-deep prologue: 8 loads/wave in flight
  stage(0, 0);
  stage(1, 1);
  for (int kt = 0; kt < 32; ++kt) {
    // wait for stage(kt)'s 4 loads; keep stage(kt+1)'s 4 in flight
    if (kt + 1 < 32) {
      asm volatile("s_waitcnt vmcnt(4)" ::: "memory");
    } else {
      asm volatile("s_waitcnt vmcnt(0)" ::: "memory");
    }
    __builtin_amdgcn_s_barrier();
    __builtin_amdgcn_sched_barrier(0);
    if (kt + 2 < 32) stage((kt + 2) % 3, kt + 2);

    const int buf = kt % 3;
    s16x8 af[4], bf[4];
#pragma unroll
    for (int mi = 0; mi < 4; ++mi) {
      int row = wm * 64 + mi * 16 + l15;
      int kc = lhi ^ ((row >> 1) & 3);
      af[mi] = *(const s16x8*)&ldsA[buf][row * 32 + kc * 8];
    }
#pragma unroll
    for (int ni = 0; ni < 4; ++ni) {
      int row = wn * 64 + ni * 16 + l15;
      int kc = lhi ^ ((row >> 1) & 3);
      bf[ni] = *(const s16x8*)&ldsB[buf][row * 32 + kc * 8];
    }
#pragma unroll
    for (int mi = 0; mi < 4; ++mi)
#pragma unroll
      for (int ni = 0; ni < 4; ++ni)
        acc[mi][ni] = MFMA16(af[mi], bf[ni], acc[mi][ni]);
  }

  // C layout: col = lane&15, row = (lane>>4)*4 + i
  if constexpr (MODE == 0) {
    float* dst = (float*)dstQ;
#pragma unroll
    for (int mi = 0; mi < 4; ++mi)
#pragma unroll
      for (int ni = 0; ni < 4; ++ni)
#pragma unroll
        for (int i = 0; i < 4; ++i) {
          int r = m0 + wm * 64 + mi * 16 + lhi * 4 + i;
          int n = n0 + wn * 64 + ni * 16 + l15;
          dst[(size_t)r * 1024 + n] = acc[mi][ni][i];
        }
  } else {  // MODE 3: fused QKV epilogue
    const int which = n0 >> 10;                 // 0=Q 1=K 2=V (uniform per block)
    if (which < 2) {
      unsigned short* dst = (unsigned short*)(which == 0 ? dstQ : dstK);
      const float sc = (which == 0) ? scale : 1.0f;
#pragma unroll
      for (int mi = 0; mi < 4; ++mi)
#pragma unroll
        for (int ni = 0; ni < 4; ++ni)
#pragma unroll
          for (int i = 0; i < 4; ++i) {
            int r = m0 + wm * 64 + mi * 16 + lhi * 4 + i;
            int nn = (n0 & 1023) + wn * 64 + ni * 16 + l15;
            float v = acc[mi][ni][i];
            float p = __shfl_xor(v, 1);         // RoPE partner
            int s = r & (SLEN - 1);
            int d = nn & 63;
            int fi = d >> 1;
            float c = ctab[s * 32 + fi], sn = stab[s * 32 + fi];
            float o = (d & 1) ? (p * sn + v * c) : (v * c - p * sn);
            o *= sc;
            int b = r >> 11, h = nn >> 6;
            dst[((size_t)(b * NHEADS + h) * SLEN + s) * 64 + d] = f2bf(o);
          }
    } else {  // V^T [bh][d][s]
      unsigned short* dst = (unsigned short*)dstV;
#pragma unroll
      for (int mi = 0; mi < 4; ++mi)
#pragma unroll
        for (int ni = 0; ni < 4; ++ni) {
          int r0 = m0 + wm * 64 + mi * 16 + lhi * 4;
          int nn = (n0 & 1023) + wn * 64 + ni * 16 + l15;
          int b = r0 >> 11, s0 = r0 & (SLEN - 1);
          int h = nn >> 6, d = nn & 63;
          s16x4 pk;
#pragma unroll
          for (int i = 0; i < 4; ++i) pk[i] = (short)f2bf(acc[mi][ni][i]);
          *(s16x4*)&dst[((size_t)(b * NHEADS + h) * 64 + d) * SLEN + s0] = pk;
        }
    }
  }
}

// ---------------- causal flash attention, v9: 32x32 swapped-QK ----------------
// Identical structure to v8. v9 change: amdgpu_waves_per_eu(4,4) pins the
// occupancy target to exactly 4 waves/SIMD (the LDS limit), so the register
// allocator stops minimizing toward 8 waves/SIMD (R10: VGPR collapsed to 64
// -> sacc+accT alone = 64 regs -> scratch spills, 62->90 us, FETCH +3MB).
// With max=4 declared the budget is 128 VGPRs; live state ~100 fits.
__global__ void __launch_bounds__(256)
__attribute__((amdgpu_waves_per_eu(4, 4)))
flash_attn(const unsigned short* __restrict__ Q,
           const unsigned short* __restrict__ K,
           const unsigned short* __restrict__ Vt,
           unsigned short* __restrict__ Obf) {
  __shared__ unsigned short Kbuf[2][64 * 64];   // 8 KB each
  __shared__ unsigned short Vbuf[2][64 * 64];   // rows = d, cols = k-local

  const int tid = threadIdx.x, lane = tid & 63, w = tid >> 6;
  const int l31 = lane & 31, h = lane >> 5;     // h: which 32-lane half

  // XCD chunking by bh + LPT (t descending in dispatch order)
  int id = blockIdx.x;                          // 0..1023
  int xcd = id & 7, idx = id >> 3;              // idx 0..127
  const int bh = xcd * 8 + (idx & 7);           // XCD k owns bh [8k, 8k+8)
  const int t = 15 - (idx >> 3);                // big q-tiles dispatched first
  const int b = bh >> 4, hd = bh & 15;

  const unsigned short* Qb = Q + (size_t)bh * SLEN * 64;
  const unsigned short* Kb = K + (size_t)bh * SLEN * 64;
  const unsigned short* Vb = Vt + (size_t)bh * 64 * SLEN;

  const int qbase = t * 128;
  const int nt = 2 * t + 2;                     // k-tiles incl. diagonal
  const int q_abs = qbase + w * 32 + l31;       // this lane's q column
  const int qminw = qbase + w * 32;             // wave's smallest q

  // stage one 64x64 K tile + one 64x64 Vt tile (16 instrs = 4/wave)
  auto stageKV = [&](int buf, int k0) {
#pragma unroll
    for (int i = 0; i < 2; ++i) {
      int c = i * 256 + tid;                    // 16B chunk 0..511
      int row = c >> 3, cg = c & 7;
      int col = ((cg ^ SWZ(row)) * 8);
      gload_lds16(Kb + (size_t)(k0 + row) * 64 + col, &Kbuf[buf][c * 8]);
      gload_lds16(Vb + (size_t)row * SLEN + k0 + col, &Vbuf[buf][c * 8]);
    }
  };

  // Q B-fragments: lane holds Q[q_abs][dc*16 + h*8 + j]
  s16x8 qf[4];
#pragma unroll
  for (int dc = 0; dc < 4; ++dc)
    qf[dc] = *(const s16x8*)&Qb[(size_t)q_abs * 64 + dc * 16 + h * 8];

  f32x16 accT[2] = {};                          // O^T: d = db*32+(r&3)+8*(r>>2)+4h
  float m_run = -3.0e38f, l_run = 0.f;

  stageKV(0, 0);
  for (int kt = 0; kt < nt; ++kt) {
    const int cur = kt & 1;
    const int k0 = kt * 64;
    if (kt + 1 < nt) {
      stageKV(cur ^ 1, (kt + 1) * 64);
      asm volatile("s_waitcnt vmcnt(4)" ::: "memory");   // stage(kt) landed; (kt+1) in flight
    } else {
      asm volatile("s_waitcnt vmcnt(0)" ::: "memory");
    }
    __builtin_amdgcn_s_barrier();
    __builtin_amdgcn_sched_barrier(0);

    {
      // S^T = K * Q^T : two 32-k blocks
      f32x16 sacc[2] = {};
#pragma unroll
      for (int kb = 0; kb < 2; ++kb) {
#pragma unroll
        for (int dc = 0; dc < 4; ++dc) {
          int r = kb * 32 + l31;
          int g = dc * 2 + h;
          s16x8 kf = *(const s16x8*)&Kbuf[cur][r * 64 + ((g ^ SWZ(r)) * 8)];
          sacc[kb] = MFMA32(kf, qf[dc], sacc[kb]);
        }
      }

      // causal mask on tiles overlapping the wave's q range
      // (k row of element r = (r&3)+8*(r>>2)+4h)
      if (k0 + 63 > qminw) {
#pragma unroll
        for (int kb = 0; kb < 2; ++kb)
#pragma unroll
          for (int r = 0; r < 16; ++r) {
            int k_abs = k0 + kb * 32 + (r & 3) + 8 * (r >> 2) + 4 * h;
            if (k_abs > q_abs) sacc[kb][r] = -3.0e38f;
          }
      }

      // lane-local max over 32 k + one cross-half combine
      float mx = sacc[0][0];
#pragma unroll
      for (int kb = 0; kb < 2; ++kb)
#pragma unroll
        for (int r = 0; r < 16; ++r) mx = fmaxf(mx, sacc[kb][r]);
      mx = fmaxf(mx, __shfl_xor(mx, 32));

      if (!__all(mx <= m_run)) {                // defer-rescale
        float mnew = fmaxf(m_run, mx);
        float facv = exp2f(m_run - mnew);
        m_run = mnew;
        l_run *= facv;
#pragma unroll
        for (int db = 0; db < 2; ++db)
#pragma unroll
          for (int r = 0; r < 16; ++r) accT[db][r] *= facv;
      }

      // exp2 + lane-local sum + cross-half combine
      float sum = 0.f;
#pragma unroll
      for (int kb = 0; kb < 2; ++kb)
#pragma unroll
        for (int r = 0; r < 16; ++r) {
          float p = exp2f(sacc[kb][r] - m_run);
          sacc[kb][r] = p;
          sum += p;
        }
      l_run += sum + __shfl_xor(sum, 32);

      // pack P to bf16 PV B-frags in-register.
      // Holder u32s: H[u][i], u = kb*4+q4 covers k = kb*32+8*q4+4h + {0..3}.
      unsigned Hv[8][2];
#pragma unroll
      for (int kb = 0; kb < 2; ++kb)
#pragma unroll
        for (int q4 = 0; q4 < 4; ++q4) {
          Hv[kb * 4 + q4][0] = cvt_pk_bf16(sacc[kb][q4 * 4 + 0], sacc[kb][q4 * 4 + 1]);
          Hv[kb * 4 + q4][1] = cvt_pk_bf16(sacc[kb][q4 * 4 + 2], sacc[kb][q4 * 4 + 3]);
        }
      // Frag c needs k = c*16 + 8h + j (j=0..7): j0..3 from h'=0 holder,
      // j4..7 from h'=1 holder, both at u = 2c + h (this lane's h).
      s16x8 pf[4];
#pragma unroll
      for (int c = 0; c < 4; ++c) {
        unsigned loc0 = h ? Hv[2 * c + 1][0] : Hv[2 * c][0];
        unsigned loc1 = h ? Hv[2 * c + 1][1] : Hv[2 * c][1];
        unsigned snd0 = h ? Hv[2 * c][0] : Hv[2 * c + 1][0];
        unsigned snd1 = h ? Hv[2 * c][1] : Hv[2 * c + 1][1];
        unsigned rcv0 = (unsigned)__shfl_xor((int)snd0, 32);
        unsigned rcv1 = (unsigned)__shfl_xor((int)snd1, 32);
        u32x4 tv;
        tv[0] = h ? rcv0 : loc0;                // k j0..3  (h'=0 holder)
        tv[1] = h ? rcv1 : loc1;
        tv[2] = h ? loc0 : rcv0;                // k j4..7  (h'=1 holder)
        tv[3] = h ? loc1 : rcv1;
        pf[c] = __builtin_bit_cast(s16x8, tv);
      }

      // PV: O^T += Vt (A, LDS) * P (B, regs)
#pragma unroll
      for (int db = 0; db < 2; ++db)
#pragma unroll
        for (int kc = 0; kc < 4; ++kc) {
          int r = db * 32 + l31;
          int g = kc * 2 + h;
          s16x8 vf = *(const s16x8*)&Vbuf[cur][r * 64 + ((g ^ SWZ(r)) * 8)];
          accT[db] = MFMA32(vf, pf[kc], accT[db]);
        }
    }

    __builtin_amdgcn_sched_barrier(0);
    __builtin_amdgcn_s_barrier();
  }

  // normalize (lane-local) and store O^T -> [b][s][h*64+d]
  float linv = 1.f / l_run;
#pragma unroll
  for (int db = 0; db < 2; ++db)
#pragma unroll
    for (int q4 = 0; q4 < 4; ++q4) {
      u32x2 pk;
      pk[0] = cvt_pk_bf16(accT[db][q4 * 4 + 0] * linv, accT[db][q4 * 4 + 1] * linv);
      pk[1] = cvt_pk_bf16(accT[db][q4 * 4 + 2] * linv, accT[db][q4 * 4 + 3] * linv);
      int d0 = db * 32 + 8 * q4 + 4 * h;
      *(u32x2*)&Obf[((size_t)(b * SLEN + q_abs)) * DMODEL + hd * 64 + d0] = pk;
    }
}

extern "C" void kernel_launch(void* const* d_in, const int* in_sizes, int n_in,
                              void* d_out, int out_size, void* d_ws, size_t ws_size,
                              hipStream_t stream) {
  const float* x  = (const float*)d_in[0];
  const float* Wq = (const float*)d_in[1];
  const float* Wk = (const float*)d_in[2];
  const float* Wv = (const float*)d_in[3];
  const float* Wo = (const float*)d_in[4];
  const int* pos  = (const int*)d_in[5];
  float* out = (float*)d_out;

  char* ws = (char*)d_ws;
  size_t off = 0;
  auto take = [&](size_t bytes) {
    char* p = ws + off;
    off += (bytes + 255) & ~(size_t)255;
    return p;
  };
  unsigned short* xbf  = (unsigned short*)take((size_t)MTOT * DMODEL * 2);
  unsigned short* wqkv = (unsigned short*)take((size_t)3 * DMODEL * DMODEL * 2);
  unsigned short* wobf = (unsigned short*)take((size_t)DMODEL * DMODEL * 2);
  unsigned short* Qs   = (unsigned short*)take((size_t)64 * SLEN * 64 * 2);
  unsigned short* Ks   = (unsigned short*)take((size_t)64 * SLEN * 64 * 2);
  unsigned short* Vt   = (unsigned short*)take((size_t)64 * 64 * SLEN * 2);
  unsigned short* Obf  = (unsigned short*)take((size_t)MTOT * DMODEL * 2);
  float* ctab = (float*)take((size_t)SLEN * 32 * 4);
  float* stab = (float*)take((size_t)SLEN * 32 * 4);

  rope_table<<<256, 256, 0, stream>>>(pos, ctab, stab);
  cvt_f32_bf16<<<4096, 256, 0, stream>>>(x, xbf, MTOT * DMODEL / 8);
  // Wq, Wk, Wv land contiguously as W_qkv[3072][1024]; Wo separate.
  cvt_weights<<<dim3(512, 4), 256, 0, stream>>>(
      Wq, Wk, Wv, Wo,
      wqkv, wqkv + (size_t)DMODEL * DMODEL, wqkv + (size_t)2 * DMODEL * DMODEL, wobf);

  // fused QKV projection: C[8192][3072], epilogue routes per 128-col block
  gemm_nt<3><<<dim3(24, 64), 256, 0, stream>>>(xbf, wqkv, Qs, Ks, Vt,
                                               ctab, stab, 0.18033688011112042f);

  flash_attn<<<1024, 256, 0, stream>>>(Qs, Ks, Vt, Obf);

  // final projection, fp32 output
  gemm_nt<0><<<dim3(8, 64), 256, 0, stream>>>(Obf, wobf, out, nullptr, nullptr,
                                              nullptr, nullptr, 1.0f);
}